// Round 1
// baseline (8617.600 us; speedup 1.0000x reference)
//
#include <hip/hip_runtime.h>
#include <hip/hip_bf16.h>

#define NN 50000
#define NE 800000
#define DH 128

typedef __attribute__((ext_vector_type(8))) short bf16x8;
typedef __attribute__((ext_vector_type(4))) float f32x4;
typedef __attribute__((ext_vector_type(8))) unsigned short us8;
typedef __attribute__((ext_vector_type(4))) unsigned short us4;

__device__ __forceinline__ unsigned short f2bf(float f) {
  unsigned int u = __builtin_bit_cast(unsigned int, f);
  unsigned int r = (u + 0x7FFFu + ((u >> 16) & 1u)) >> 16;
  return (unsigned short)r;
}
__device__ __forceinline__ float bf2f(unsigned short h) {
  unsigned int u = ((unsigned int)h) << 16;
  return __builtin_bit_cast(float, u);
}

// ---- convert x f32 -> bf16, 8 elems/thread ----
__global__ void k_cvt_x(const float* __restrict__ x, unsigned short* __restrict__ xb, int n8) {
  int i = blockIdx.x * blockDim.x + threadIdx.x;
  if (i >= n8) return;
  const float4* p = reinterpret_cast<const float4*>(x) + (size_t)i * 2;
  float4 a = p[0], b = p[1];
  us8 o;
  o[0] = f2bf(a.x); o[1] = f2bf(a.y); o[2] = f2bf(a.z); o[3] = f2bf(a.w);
  o[4] = f2bf(b.x); o[5] = f2bf(b.y); o[6] = f2bf(b.z); o[7] = f2bf(b.w);
  reinterpret_cast<us8*>(xb)[i] = o;
}

// ---- build Wt[c][k] = (k<128 ? wl[k][c] : wr[k-128][c]) in bf16 ----
__global__ void k_prep_w(const float* __restrict__ wl, const float* __restrict__ wr,
                         unsigned short* __restrict__ wt, int dout) {
  int idx = blockIdx.x * blockDim.x + threadIdx.x;
  if (idx >= dout * 256) return;
  int c = idx >> 8, k = idx & 255;
  float v = (k < DH) ? wl[k * dout + c] : wr[(k - DH) * dout + c];
  wt[idx] = f2bf(v);
}

// ---- degree ----
__global__ void k_deg(const int* __restrict__ dst, float* __restrict__ deg) {
  int e = blockIdx.x * blockDim.x + threadIdx.x;
  if (e < NE) atomicAdd(&deg[dst[e]], 1.0f);
}
__global__ void k_invdeg(const float* __restrict__ deg, float* __restrict__ inv) {
  int i = blockIdx.x * blockDim.x + threadIdx.x;
  if (i < NN) inv[i] = 1.0f / fmaxf(deg[i], 1.0f);
}

// ---- scatter-add: 16 threads per edge, 8 bf16 (16B) each ----
__global__ void k_scatter(const unsigned short* __restrict__ h, const int* __restrict__ src,
                          const int* __restrict__ dst, float* __restrict__ agg) {
  int t = blockIdx.x * blockDim.x + threadIdx.x;
  int e = t >> 4;
  if (e >= NE) return;
  int c = (t & 15) << 3;
  int s = src[e], d = dst[e];
  us8 v = reinterpret_cast<const us8*>(h + (size_t)s * DH)[t & 15];
  float* a = agg + (size_t)d * DH + c;
#pragma unroll
  for (int j = 0; j < 8; ++j) atomicAdd(a + j, bf2f(v[j]));
}

// ---- build A[n][0:128]=bf16(agg*inv), A[n][128:256]=hb[n]; 32 thr/node, 8 cols each ----
__global__ void k_prep_A(const float* __restrict__ agg, const float* __restrict__ inv,
                         const unsigned short* __restrict__ hb, unsigned short* __restrict__ A) {
  int t = blockIdx.x * blockDim.x + threadIdx.x;
  int n = t >> 5, q = t & 31;
  if (n >= NN) return;
  if (q < 16) {
    int c = q << 3;
    float iv = inv[n];
    const float4* p = reinterpret_cast<const float4*>(agg + (size_t)n * DH + c);
    float4 a = p[0], b = p[1];
    us8 o;
    o[0] = f2bf(a.x * iv); o[1] = f2bf(a.y * iv); o[2] = f2bf(a.z * iv); o[3] = f2bf(a.w * iv);
    o[4] = f2bf(b.x * iv); o[5] = f2bf(b.y * iv); o[6] = f2bf(b.z * iv); o[7] = f2bf(b.w * iv);
    reinterpret_cast<us8*>(A + (size_t)n * 256)[q] = o;
  } else {
    us8 v = reinterpret_cast<const us8*>(hb + (size_t)n * DH)[q - 16];
    reinterpret_cast<us8*>(A + (size_t)n * 256 + DH)[q - 16] = v;
  }
}

// ---- GEMM: [N,256]bf16 @ Wt[BN,256]bf16^T + bias -> out f32 [N,BN] ----
// BM=128 rows/block, 4 waves in WR x WC grid, 16x16x32 MFMA, no LDS (L2-resident panels)
template <int BN, int WR, int WC>
__global__ __launch_bounds__(256) void k_gemm(const unsigned short* __restrict__ A,
                                              const unsigned short* __restrict__ Wt,
                                              const float* __restrict__ bias,
                                              float* __restrict__ out) {
  constexpr int TM = 128 / WR;
  constexpr int TN = BN / WC;
  constexpr int FM = TM / 16, FN = TN / 16;
  int lane = threadIdx.x & 63;
  int w = threadIdx.x >> 6;
  int wr = w / WC, wc = w % WC;
  int rowbase = blockIdx.x * 128 + wr * TM;
  int colbase = wc * TN;
  int lr = lane & 15, lk = (lane >> 4) << 3;

  f32x4 acc[FM][FN] = {};
#pragma unroll
  for (int ks = 0; ks < 8; ++ks) {
    int k0 = (ks << 5) + lk;
    bf16x8 af[FM], bfr[FN];
#pragma unroll
    for (int i = 0; i < FM; ++i) {
      int r = rowbase + i * 16 + lr;
      r = r < NN ? r : NN - 1;
      af[i] = *reinterpret_cast<const bf16x8*>(A + (size_t)r * 256 + k0);
    }
#pragma unroll
    for (int j = 0; j < FN; ++j)
      bfr[j] = *reinterpret_cast<const bf16x8*>(Wt + (size_t)(colbase + j * 16 + lr) * 256 + k0);
#pragma unroll
    for (int i = 0; i < FM; ++i)
#pragma unroll
      for (int j = 0; j < FN; ++j)
        acc[i][j] = __builtin_amdgcn_mfma_f32_16x16x32_bf16(af[i], bfr[j], acc[i][j], 0, 0, 0);
  }
#pragma unroll
  for (int i = 0; i < FM; ++i) {
#pragma unroll
    for (int j = 0; j < FN; ++j) {
      int col = colbase + j * 16 + lr;
      float bv = bias[col];
#pragma unroll
      for (int r = 0; r < 4; ++r) {
        int row = rowbase + i * 16 + ((lane >> 4) << 2) + r;
        if (row < NN) out[(size_t)row * BN + col] = acc[i][j][r] + bv;
      }
    }
  }
}

// ---- BN column stats: sum & sumsq into stats[0:128], stats[128:256] ----
__global__ void k_bnstats(const float* __restrict__ h, float* __restrict__ stats) {
  int t = threadIdx.x;
  int col = t & (DH - 1), half = t >> 7;
  float s = 0.f, s2 = 0.f;
  for (int n = blockIdx.x * 2 + half; n < NN; n += gridDim.x * 2) {
    float v = h[(size_t)n * DH + col];
    s += v; s2 += v * v;
  }
  __shared__ float ls[256], ls2[256];
  ls[t] = s; ls2[t] = s2;
  __syncthreads();
  if (t < DH) {
    atomicAdd(&stats[t], ls[t] + ls[t + DH]);
    atomicAdd(&stats[DH + t], ls2[t] + ls2[t + DH]);
  }
}

// ---- BN apply + ReLU -> bf16 ----
__global__ void k_bnapply(const float* __restrict__ h, const float* __restrict__ stats,
                          const float* __restrict__ g, const float* __restrict__ be,
                          unsigned short* __restrict__ hb) {
  int i = blockIdx.x * blockDim.x + threadIdx.x;
  if (i >= NN * DH / 4) return;
  int c = (i * 4) & (DH - 1);
  float4 v = reinterpret_cast<const float4*>(h)[i];
  float vv[4] = {v.x, v.y, v.z, v.w};
  us4 o;
#pragma unroll
  for (int j = 0; j < 4; ++j) {
    float mu = stats[c + j] * (1.0f / NN);
    float var = stats[DH + c + j] * (1.0f / NN) - mu * mu;
    float rs = rsqrtf(var + 1e-5f);
    float val = (vv[j] - mu) * rs * g[c + j] + be[c + j];
    o[j] = f2bf(fmaxf(val, 0.0f));
  }
  reinterpret_cast<us4*>(hb)[i] = o;
}

extern "C" void kernel_launch(void* const* d_in, const int* in_sizes, int n_in,
                              void* d_out, int out_size, void* d_ws, size_t ws_size,
                              hipStream_t stream) {
  const float* x = (const float*)d_in[0];
  const int* ei = (const int*)d_in[1];
  const int* srcp = ei;
  const int* dstp = ei + NE;
  const float* w1l = (const float*)d_in[2];
  const float* w1r = (const float*)d_in[3];
  const float* b1 = (const float*)d_in[4];
  const float* g1 = (const float*)d_in[5];
  const float* be1 = (const float*)d_in[6];
  const float* w2l = (const float*)d_in[7];
  const float* w2r = (const float*)d_in[8];
  const float* b2 = (const float*)d_in[9];
  const float* g2 = (const float*)d_in[10];
  const float* be2 = (const float*)d_in[11];
  const float* w3l = (const float*)d_in[12];
  const float* w3r = (const float*)d_in[13];
  const float* b3 = (const float*)d_in[14];

  char* ws = (char*)d_ws;
  size_t off = 0;
  auto alloc = [&](size_t bytes) {
    char* p = ws + off;
    off = (off + bytes + 255) & ~(size_t)255;
    return p;
  };
  unsigned short* xb = (unsigned short*)alloc((size_t)NN * DH * 2);
  unsigned short* h1 = (unsigned short*)alloc((size_t)NN * DH * 2);
  unsigned short* h2 = (unsigned short*)alloc((size_t)NN * DH * 2);
  unsigned short* Ab = (unsigned short*)alloc((size_t)NN * 256 * 2);
  float* agg = (float*)alloc((size_t)NN * DH * 4);  // reused as gemm output
  unsigned short* w1t = (unsigned short*)alloc(128 * 256 * 2);
  unsigned short* w2t = (unsigned short*)alloc(128 * 256 * 2);
  unsigned short* w3t = (unsigned short*)alloc(64 * 256 * 2);
  float* deg = (float*)alloc(NN * 4);
  float* invd = (float*)alloc(NN * 4);
  float* stats = (float*)alloc(2 * DH * 4);

  hipMemsetAsync(deg, 0, NN * 4, stream);
  k_cvt_x<<<(NN * DH / 8 + 255) / 256, 256, 0, stream>>>(x, xb, NN * DH / 8);
  k_prep_w<<<128, 256, 0, stream>>>(w1l, w1r, w1t, 128);
  k_prep_w<<<128, 256, 0, stream>>>(w2l, w2r, w2t, 128);
  k_prep_w<<<64, 256, 0, stream>>>(w3l, w3r, w3t, 64);
  k_deg<<<(NE + 255) / 256, 256, 0, stream>>>(dstp, deg);
  k_invdeg<<<(NN + 255) / 256, 256, 0, stream>>>(deg, invd);

  int gemm_blocks = (NN + 127) / 128;

  // ---- layer 1 ----
  hipMemsetAsync(agg, 0, (size_t)NN * DH * 4, stream);
  k_scatter<<<NE * 16 / 256, 256, 0, stream>>>(xb, srcp, dstp, agg);
  k_prep_A<<<NN * 32 / 256, 256, 0, stream>>>(agg, invd, xb, Ab);
  k_gemm<128, 2, 2><<<gemm_blocks, 256, 0, stream>>>(Ab, w1t, b1, agg);
  hipMemsetAsync(stats, 0, 2 * DH * 4, stream);
  k_bnstats<<<256, 256, 0, stream>>>(agg, stats);
  k_bnapply<<<NN * DH / 4 / 256 + 1, 256, 0, stream>>>(agg, stats, g1, be1, h1);

  // ---- layer 2 ----
  hipMemsetAsync(agg, 0, (size_t)NN * DH * 4, stream);
  k_scatter<<<NE * 16 / 256, 256, 0, stream>>>(h1, srcp, dstp, agg);
  k_prep_A<<<NN * 32 / 256, 256, 0, stream>>>(agg, invd, h1, Ab);
  k_gemm<128, 2, 2><<<gemm_blocks, 256, 0, stream>>>(Ab, w2t, b2, agg);
  hipMemsetAsync(stats, 0, 2 * DH * 4, stream);
  k_bnstats<<<256, 256, 0, stream>>>(agg, stats);
  k_bnapply<<<NN * DH / 4 / 256 + 1, 256, 0, stream>>>(agg, stats, g2, be2, h2);

  // ---- layer 3 ----
  hipMemsetAsync(agg, 0, (size_t)NN * DH * 4, stream);
  k_scatter<<<NE * 16 / 256, 256, 0, stream>>>(h2, srcp, dstp, agg);
  k_prep_A<<<NN * 32 / 256, 256, 0, stream>>>(agg, invd, h2, Ab);
  k_gemm<64, 4, 1><<<gemm_blocks, 256, 0, stream>>>(Ab, w3t, b3, (float*)d_out);
}

// Round 2
// 498.379 us; speedup vs baseline: 17.2913x; 17.2913x over previous
//
#include <hip/hip_runtime.h>
#include <hip/hip_bf16.h>

#define NN 50000
#define NE 800000
#define DH 128

typedef __attribute__((ext_vector_type(8))) short bf16x8;
typedef __attribute__((ext_vector_type(4))) float f32x4;
typedef __attribute__((ext_vector_type(8))) unsigned short us8;
typedef __attribute__((ext_vector_type(4))) unsigned short us4;

__device__ __forceinline__ unsigned short f2bf(float f) {
  unsigned int u = __builtin_bit_cast(unsigned int, f);
  unsigned int r = (u + 0x7FFFu + ((u >> 16) & 1u)) >> 16;
  return (unsigned short)r;
}
__device__ __forceinline__ float bf2f(unsigned int h16) {
  unsigned int u = h16 << 16;
  return __builtin_bit_cast(float, u);
}

// ---- convert x f32 -> bf16, 8 elems/thread ----
__global__ void k_cvt_x(const float* __restrict__ x, unsigned short* __restrict__ xb, int n8) {
  int i = blockIdx.x * blockDim.x + threadIdx.x;
  if (i >= n8) return;
  const float4* p = reinterpret_cast<const float4*>(x) + (size_t)i * 2;
  float4 a = p[0], b = p[1];
  us8 o;
  o[0] = f2bf(a.x); o[1] = f2bf(a.y); o[2] = f2bf(a.z); o[3] = f2bf(a.w);
  o[4] = f2bf(b.x); o[5] = f2bf(b.y); o[6] = f2bf(b.z); o[7] = f2bf(b.w);
  reinterpret_cast<us8*>(xb)[i] = o;
}

// ---- build Wt[c][k] = (k<128 ? wl[k][c] : wr[k-128][c]) in bf16 ----
__global__ void k_prep_w(const float* __restrict__ wl, const float* __restrict__ wr,
                         unsigned short* __restrict__ wt, int dout) {
  int idx = blockIdx.x * blockDim.x + threadIdx.x;
  if (idx >= dout * 256) return;
  int c = idx >> 8, k = idx & 255;
  float v = (k < DH) ? wl[k * dout + c] : wr[(k - DH) * dout + c];
  wt[idx] = f2bf(v);
}

// ---- CSR build ----
__global__ void k_deg(const int* __restrict__ dst, int* __restrict__ deg) {
  int e = blockIdx.x * blockDim.x + threadIdx.x;
  if (e < NE) atomicAdd(&deg[dst[e]], 1);
}

__global__ void k_scan(const int* __restrict__ deg, int* __restrict__ rowptr,
                       int* __restrict__ cursor, float* __restrict__ invd) {
  __shared__ int sums[256];
  int t = threadIdx.x;
  const int chunk = (NN + 255) / 256;
  int lo = t * chunk, hi = lo + chunk;
  if (hi > NN) hi = NN;
  int s = 0;
  for (int i = lo; i < hi; ++i) s += deg[i];
  sums[t] = s;
  __syncthreads();
  for (int off = 1; off < 256; off <<= 1) {
    int v = (t >= off) ? sums[t - off] : 0;
    __syncthreads();
    sums[t] += v;
    __syncthreads();
  }
  int base = (t == 0) ? 0 : sums[t - 1];
  for (int i = lo; i < hi; ++i) {
    rowptr[i] = base;
    cursor[i] = base;
    int d = deg[i];
    invd[i] = 1.0f / (float)(d > 0 ? d : 1);
    base += d;
  }
  if (t == 255) rowptr[NN] = base;
}

__global__ void k_fill(const int* __restrict__ src, const int* __restrict__ dst,
                       int* __restrict__ cursor, int* __restrict__ adj) {
  int e = blockIdx.x * blockDim.x + threadIdx.x;
  if (e < NE) {
    int p = atomicAdd(&cursor[dst[e]], 1);
    adj[p] = src[e];
  }
}

// ---- gather-mean aggregation: one wave per node, lane owns 2 cols (4B) ----
__global__ __launch_bounds__(256) void k_agg(const unsigned short* __restrict__ h,
                                             const int* __restrict__ rowptr,
                                             const int* __restrict__ adj,
                                             const float* __restrict__ invd,
                                             unsigned short* __restrict__ meanb) {
  int wid = (blockIdx.x * blockDim.x + threadIdx.x) >> 6;
  int lane = threadIdx.x & 63;
  if (wid >= NN) return;
  int lo = rowptr[wid], hi = rowptr[wid + 1];
  int c = lane << 1;
  float ax = 0.f, ay = 0.f;
  int e = lo;
  // 4-deep unroll for MLP
  for (; e + 4 <= hi; e += 4) {
    int s0 = adj[e], s1 = adj[e + 1], s2 = adj[e + 2], s3 = adj[e + 3];
    unsigned int v0 = *reinterpret_cast<const unsigned int*>(h + (size_t)s0 * DH + c);
    unsigned int v1 = *reinterpret_cast<const unsigned int*>(h + (size_t)s1 * DH + c);
    unsigned int v2 = *reinterpret_cast<const unsigned int*>(h + (size_t)s2 * DH + c);
    unsigned int v3 = *reinterpret_cast<const unsigned int*>(h + (size_t)s3 * DH + c);
    ax += bf2f(v0 & 0xffff) + bf2f(v1 & 0xffff) + bf2f(v2 & 0xffff) + bf2f(v3 & 0xffff);
    ay += bf2f(v0 >> 16) + bf2f(v1 >> 16) + bf2f(v2 >> 16) + bf2f(v3 >> 16);
  }
  for (; e < hi; ++e) {
    int s = adj[e];
    unsigned int v = *reinterpret_cast<const unsigned int*>(h + (size_t)s * DH + c);
    ax += bf2f(v & 0xffff);
    ay += bf2f(v >> 16);
  }
  float iv = invd[wid];
  unsigned int o = (unsigned int)f2bf(ax * iv) | ((unsigned int)f2bf(ay * iv) << 16);
  *reinterpret_cast<unsigned int*>(meanb + (size_t)wid * DH + c) = o;
}

// ---- GEMM: [mean|h][N,256]bf16 @ Wt[BN,256]^T + bias -> out f32 [N,BN] ----
template <int BN, int WR, int WC>
__global__ __launch_bounds__(256) void k_gemm(const unsigned short* __restrict__ Am,
                                              const unsigned short* __restrict__ Ah,
                                              const unsigned short* __restrict__ Wt,
                                              const float* __restrict__ bias,
                                              float* __restrict__ out) {
  constexpr int TM = 128 / WR;
  constexpr int TN = BN / WC;
  constexpr int FM = TM / 16, FN = TN / 16;
  int lane = threadIdx.x & 63;
  int w = threadIdx.x >> 6;
  int wr = w / WC, wc = w % WC;
  int rowbase = blockIdx.x * 128 + wr * TM;
  int colbase = wc * TN;
  int lr = lane & 15, lk = (lane >> 4) << 3;

  f32x4 acc[FM][FN] = {};
#pragma unroll
  for (int ks = 0; ks < 8; ++ks) {
    const unsigned short* Ab = (ks < 4) ? Am : Ah;
    int ka = ((ks & 3) << 5) + lk;
    int kw = (ks << 5) + lk;
    bf16x8 af[FM], bfr[FN];
#pragma unroll
    for (int i = 0; i < FM; ++i) {
      int r = rowbase + i * 16 + lr;
      r = r < NN ? r : NN - 1;
      af[i] = *reinterpret_cast<const bf16x8*>(Ab + (size_t)r * DH + ka);
    }
#pragma unroll
    for (int j = 0; j < FN; ++j)
      bfr[j] = *reinterpret_cast<const bf16x8*>(Wt + (size_t)(colbase + j * 16 + lr) * 256 + kw);
#pragma unroll
    for (int i = 0; i < FM; ++i)
#pragma unroll
      for (int j = 0; j < FN; ++j)
        acc[i][j] = __builtin_amdgcn_mfma_f32_16x16x32_bf16(af[i], bfr[j], acc[i][j], 0, 0, 0);
  }
#pragma unroll
  for (int i = 0; i < FM; ++i) {
#pragma unroll
    for (int j = 0; j < FN; ++j) {
      int col = colbase + j * 16 + lr;
      float bv = bias[col];
#pragma unroll
      for (int r = 0; r < 4; ++r) {
        int row = rowbase + i * 16 + ((lane >> 4) << 2) + r;
        if (row < NN) out[(size_t)row * BN + col] = acc[i][j][r] + bv;
      }
    }
  }
}

// ---- BN column stats: sum & sumsq into stats[0:128], stats[128:256] ----
__global__ void k_bnstats(const float* __restrict__ h, float* __restrict__ stats) {
  int t = threadIdx.x;
  int col = t & (DH - 1), half = t >> 7;
  float s = 0.f, s2 = 0.f;
  for (int n = blockIdx.x * 2 + half; n < NN; n += gridDim.x * 2) {
    float v = h[(size_t)n * DH + col];
    s += v; s2 += v * v;
  }
  __shared__ float ls[256], ls2[256];
  ls[t] = s; ls2[t] = s2;
  __syncthreads();
  if (t < DH) {
    atomicAdd(&stats[t], ls[t] + ls[t + DH]);
    atomicAdd(&stats[DH + t], ls2[t] + ls2[t + DH]);
  }
}

// ---- BN apply + ReLU -> bf16 ----
__global__ void k_bnapply(const float* __restrict__ h, const float* __restrict__ stats,
                          const float* __restrict__ g, const float* __restrict__ be,
                          unsigned short* __restrict__ hb) {
  int i = blockIdx.x * blockDim.x + threadIdx.x;
  if (i >= NN * DH / 4) return;
  int c = (i * 4) & (DH - 1);
  float4 v = reinterpret_cast<const float4*>(h)[i];
  float vv[4] = {v.x, v.y, v.z, v.w};
  us4 o;
#pragma unroll
  for (int j = 0; j < 4; ++j) {
    float mu = stats[c + j] * (1.0f / NN);
    float var = stats[DH + c + j] * (1.0f / NN) - mu * mu;
    float rs = rsqrtf(var + 1e-5f);
    float val = (vv[j] - mu) * rs * g[c + j] + be[c + j];
    o[j] = f2bf(fmaxf(val, 0.0f));
  }
  reinterpret_cast<us4*>(hb)[i] = o;
}

extern "C" void kernel_launch(void* const* d_in, const int* in_sizes, int n_in,
                              void* d_out, int out_size, void* d_ws, size_t ws_size,
                              hipStream_t stream) {
  const float* x = (const float*)d_in[0];
  const int* ei = (const int*)d_in[1];
  const int* srcp = ei;
  const int* dstp = ei + NE;
  const float* w1l = (const float*)d_in[2];
  const float* w1r = (const float*)d_in[3];
  const float* b1 = (const float*)d_in[4];
  const float* g1 = (const float*)d_in[5];
  const float* be1 = (const float*)d_in[6];
  const float* w2l = (const float*)d_in[7];
  const float* w2r = (const float*)d_in[8];
  const float* b2 = (const float*)d_in[9];
  const float* g2 = (const float*)d_in[10];
  const float* be2 = (const float*)d_in[11];
  const float* w3l = (const float*)d_in[12];
  const float* w3r = (const float*)d_in[13];
  const float* b3 = (const float*)d_in[14];

  char* ws = (char*)d_ws;
  size_t off = 0;
  auto alloc = [&](size_t bytes) {
    char* p = ws + off;
    off = (off + bytes + 255) & ~(size_t)255;
    return p;
  };
  unsigned short* xb = (unsigned short*)alloc((size_t)NN * DH * 2);
  unsigned short* h1 = (unsigned short*)alloc((size_t)NN * DH * 2);
  unsigned short* h2 = (unsigned short*)alloc((size_t)NN * DH * 2);
  unsigned short* meanb = (unsigned short*)alloc((size_t)NN * DH * 2);
  float* gout = (float*)alloc((size_t)NN * DH * 4);
  unsigned short* w1t = (unsigned short*)alloc(128 * 256 * 2);
  unsigned short* w2t = (unsigned short*)alloc(128 * 256 * 2);
  unsigned short* w3t = (unsigned short*)alloc(64 * 256 * 2);
  int* deg = (int*)alloc(NN * 4);
  int* rowptr = (int*)alloc((NN + 1) * 4);
  int* cursor = (int*)alloc(NN * 4);
  int* adj = (int*)alloc((size_t)NE * 4);
  float* invd = (float*)alloc(NN * 4);
  float* stats = (float*)alloc(2 * DH * 4);

  // ---- one-time prep ----
  hipMemsetAsync(deg, 0, NN * 4, stream);
  k_cvt_x<<<(NN * DH / 8 + 255) / 256, 256, 0, stream>>>(x, xb, NN * DH / 8);
  k_prep_w<<<128, 256, 0, stream>>>(w1l, w1r, w1t, 128);
  k_prep_w<<<128, 256, 0, stream>>>(w2l, w2r, w2t, 128);
  k_prep_w<<<64, 256, 0, stream>>>(w3l, w3r, w3t, 64);
  k_deg<<<(NE + 255) / 256, 256, 0, stream>>>(dstp, deg);
  k_scan<<<1, 256, 0, stream>>>(deg, rowptr, cursor, invd);
  k_fill<<<(NE + 255) / 256, 256, 0, stream>>>(srcp, dstp, cursor, adj);

  int agg_blocks = (NN * 64 + 255) / 256;
  int gemm_blocks = (NN + 127) / 128;

  // ---- layer 1 ----
  k_agg<<<agg_blocks, 256, 0, stream>>>(xb, rowptr, adj, invd, meanb);
  k_gemm<128, 2, 2><<<gemm_blocks, 256, 0, stream>>>(meanb, xb, w1t, b1, gout);
  hipMemsetAsync(stats, 0, 2 * DH * 4, stream);
  k_bnstats<<<256, 256, 0, stream>>>(gout, stats);
  k_bnapply<<<(NN * DH / 4 + 255) / 256, 256, 0, stream>>>(gout, stats, g1, be1, h1);

  // ---- layer 2 ----
  k_agg<<<agg_blocks, 256, 0, stream>>>(h1, rowptr, adj, invd, meanb);
  k_gemm<128, 2, 2><<<gemm_blocks, 256, 0, stream>>>(meanb, h1, w2t, b2, gout);
  hipMemsetAsync(stats, 0, 2 * DH * 4, stream);
  k_bnstats<<<256, 256, 0, stream>>>(gout, stats);
  k_bnapply<<<(NN * DH / 4 + 255) / 256, 256, 0, stream>>>(gout, stats, g2, be2, h2);

  // ---- layer 3 ----
  k_agg<<<agg_blocks, 256, 0, stream>>>(h2, rowptr, adj, invd, meanb);
  k_gemm<64, 4, 1><<<gemm_blocks, 256, 0, stream>>>(meanb, h2, w3t, b3, (float*)d_out);
}

// Round 3
// 352.942 us; speedup vs baseline: 24.4164x; 1.4121x over previous
//
#include <hip/hip_runtime.h>
#include <hip/hip_bf16.h>

#define NN 50000
#define NE 800000
#define DH 128
#define NB1 196  // ceil(NN/256)

typedef __attribute__((ext_vector_type(8))) short bf16x8;
typedef __attribute__((ext_vector_type(4))) float f32x4;
typedef __attribute__((ext_vector_type(8))) unsigned short us8;
typedef __attribute__((ext_vector_type(4))) unsigned short us4;

__device__ __forceinline__ unsigned short f2bf(float f) {
  unsigned int u = __builtin_bit_cast(unsigned int, f);
  unsigned int r = (u + 0x7FFFu + ((u >> 16) & 1u)) >> 16;
  return (unsigned short)r;
}
__device__ __forceinline__ float bf2f(unsigned int h16) {
  unsigned int u = h16 << 16;
  return __builtin_bit_cast(float, u);
}

// ---- convert x f32 -> bf16, 8 elems/thread ----
__global__ void k_cvt_x(const float* __restrict__ x, unsigned short* __restrict__ xb, int n8) {
  int i = blockIdx.x * blockDim.x + threadIdx.x;
  if (i >= n8) return;
  const float4* p = reinterpret_cast<const float4*>(x) + (size_t)i * 2;
  float4 a = p[0], b = p[1];
  us8 o;
  o[0] = f2bf(a.x); o[1] = f2bf(a.y); o[2] = f2bf(a.z); o[3] = f2bf(a.w);
  o[4] = f2bf(b.x); o[5] = f2bf(b.y); o[6] = f2bf(b.z); o[7] = f2bf(b.w);
  reinterpret_cast<us8*>(xb)[i] = o;
}

// ---- build Wt[c][k] = (k<128 ? wl[k][c] : wr[k-128][c]) in bf16 ----
__global__ void k_prep_w(const float* __restrict__ wl, const float* __restrict__ wr,
                         unsigned short* __restrict__ wt, int dout) {
  int idx = blockIdx.x * blockDim.x + threadIdx.x;
  if (idx >= dout * 256) return;
  int c = idx >> 8, k = idx & 255;
  float v = (k < DH) ? wl[k * dout + c] : wr[(k - DH) * dout + c];
  wt[idx] = f2bf(v);
}

// ---- CSR build ----
__global__ void k_deg(const int* __restrict__ dst, int* __restrict__ deg) {
  int e = blockIdx.x * blockDim.x + threadIdx.x;
  if (e < NE) atomicAdd(&deg[dst[e]], 1);
}

// per-block inclusive scan of deg, block totals to bsum
__global__ void k_scan1(const int* __restrict__ deg, int* __restrict__ iscan,
                        int* __restrict__ bsum) {
  __shared__ int s[256];
  int t = threadIdx.x;
  int i = blockIdx.x * 256 + t;
  int d = (i < NN) ? deg[i] : 0;
  s[t] = d;
  __syncthreads();
  for (int off = 1; off < 256; off <<= 1) {
    int v = (t >= off) ? s[t - off] : 0;
    __syncthreads();
    s[t] += v;
    __syncthreads();
  }
  if (i < NN) iscan[i] = s[t];
  if (t == 255) bsum[blockIdx.x] = s[255];
}

// exclusive scan of the NB1 block sums (single block)
__global__ void k_scan2(int* __restrict__ bsum) {
  __shared__ int s[256];
  int t = threadIdx.x;
  int v = (t < NB1) ? bsum[t] : 0;
  s[t] = v;
  __syncthreads();
  for (int off = 1; off < 256; off <<= 1) {
    int u = (t >= off) ? s[t - off] : 0;
    __syncthreads();
    s[t] += u;
    __syncthreads();
  }
  if (t < NB1) bsum[t] = s[t] - v;
}

// apply block prefixes -> rowptr/cursor/invd
__global__ void k_scan3(const int* __restrict__ deg, const int* __restrict__ iscan,
                        const int* __restrict__ bsum, int* __restrict__ rowptr,
                        int* __restrict__ cursor, float* __restrict__ invd) {
  int i = blockIdx.x * 256 + threadIdx.x;
  if (i >= NN) return;
  int d = deg[i];
  int excl = bsum[blockIdx.x] + iscan[i] - d;
  rowptr[i] = excl;
  cursor[i] = excl;
  invd[i] = 1.0f / (float)(d > 0 ? d : 1);
  if (i == 0) rowptr[NN] = NE;
}

__global__ void k_fill(const int* __restrict__ src, const int* __restrict__ dst,
                       int* __restrict__ cursor, int* __restrict__ adj) {
  int e = blockIdx.x * blockDim.x + threadIdx.x;
  if (e < NE) {
    int p = atomicAdd(&cursor[dst[e]], 1);
    adj[p] = src[e];
  }
}

// ---- gather-mean: one wave per node; two 32-lane halves process 2 edges/step,
//      each lane loads 8B (4 cols); cross-half combine via shfl ----
__global__ __launch_bounds__(256) void k_agg(const unsigned short* __restrict__ h,
                                             const int* __restrict__ rowptr,
                                             const int* __restrict__ adj,
                                             const float* __restrict__ invd,
                                             unsigned short* __restrict__ meanb) {
  int wid = (blockIdx.x * blockDim.x + threadIdx.x) >> 6;
  int lane = threadIdx.x & 63;
  if (wid >= NN) return;
  int lo = rowptr[wid], hi = rowptr[wid + 1];
  int half = lane >> 5;
  int c = (lane & 31) << 2;
  float a0 = 0.f, a1 = 0.f, a2 = 0.f, a3 = 0.f;
  int e = lo;
#pragma unroll 2
  for (; e + 2 <= hi; e += 2) {
    int s = adj[e + half];
    us4 v = *reinterpret_cast<const us4*>(h + (size_t)s * DH + c);
    a0 += bf2f(v[0]); a1 += bf2f(v[1]); a2 += bf2f(v[2]); a3 += bf2f(v[3]);
  }
  if (e < hi && half == 0) {
    int s = adj[e];
    us4 v = *reinterpret_cast<const us4*>(h + (size_t)s * DH + c);
    a0 += bf2f(v[0]); a1 += bf2f(v[1]); a2 += bf2f(v[2]); a3 += bf2f(v[3]);
  }
  a0 += __shfl_down(a0, 32);
  a1 += __shfl_down(a1, 32);
  a2 += __shfl_down(a2, 32);
  a3 += __shfl_down(a3, 32);
  if (half == 0) {
    float iv = invd[wid];
    us4 o;
    o[0] = f2bf(a0 * iv); o[1] = f2bf(a1 * iv);
    o[2] = f2bf(a2 * iv); o[3] = f2bf(a3 * iv);
    *reinterpret_cast<us4*>(meanb + (size_t)wid * DH + c) = o;
  }
}

// ---- GEMM: [mean|h][N,256]bf16 @ Wt[BN,256]^T + bias -> out f32 [N,BN] ----
template <int BN, int WR, int WC>
__global__ __launch_bounds__(256) void k_gemm(const unsigned short* __restrict__ Am,
                                              const unsigned short* __restrict__ Ah,
                                              const unsigned short* __restrict__ Wt,
                                              const float* __restrict__ bias,
                                              float* __restrict__ out) {
  constexpr int TM = 128 / WR;
  constexpr int TN = BN / WC;
  constexpr int FM = TM / 16, FN = TN / 16;
  int lane = threadIdx.x & 63;
  int w = threadIdx.x >> 6;
  int wr = w / WC, wc = w % WC;
  int rowbase = blockIdx.x * 128 + wr * TM;
  int colbase = wc * TN;
  int lr = lane & 15, lk = (lane >> 4) << 3;

  f32x4 acc[FM][FN] = {};
#pragma unroll
  for (int ks = 0; ks < 8; ++ks) {
    const unsigned short* Ab = (ks < 4) ? Am : Ah;
    int ka = ((ks & 3) << 5) + lk;
    int kw = (ks << 5) + lk;
    bf16x8 af[FM], bfr[FN];
#pragma unroll
    for (int i = 0; i < FM; ++i) {
      int r = rowbase + i * 16 + lr;
      r = r < NN ? r : NN - 1;
      af[i] = *reinterpret_cast<const bf16x8*>(Ab + (size_t)r * DH + ka);
    }
#pragma unroll
    for (int j = 0; j < FN; ++j)
      bfr[j] = *reinterpret_cast<const bf16x8*>(Wt + (size_t)(colbase + j * 16 + lr) * 256 + kw);
#pragma unroll
    for (int i = 0; i < FM; ++i)
#pragma unroll
      for (int j = 0; j < FN; ++j)
        acc[i][j] = __builtin_amdgcn_mfma_f32_16x16x32_bf16(af[i], bfr[j], acc[i][j], 0, 0, 0);
  }
#pragma unroll
  for (int i = 0; i < FM; ++i) {
#pragma unroll
    for (int j = 0; j < FN; ++j) {
      int col = colbase + j * 16 + lr;
      float bv = bias[col];
#pragma unroll
      for (int r = 0; r < 4; ++r) {
        int row = rowbase + i * 16 + ((lane >> 4) << 2) + r;
        if (row < NN) out[(size_t)row * BN + col] = acc[i][j][r] + bv;
      }
    }
  }
}

// ---- BN column stats: sum & sumsq into stats[0:128], stats[128:256] ----
__global__ void k_bnstats(const float* __restrict__ h, float* __restrict__ stats) {
  int t = threadIdx.x;
  int col = t & (DH - 1), half = t >> 7;
  float s = 0.f, s2 = 0.f;
  for (int n = blockIdx.x * 2 + half; n < NN; n += gridDim.x * 2) {
    float v = h[(size_t)n * DH + col];
    s += v; s2 += v * v;
  }
  __shared__ float ls[256], ls2[256];
  ls[t] = s; ls2[t] = s2;
  __syncthreads();
  if (t < DH) {
    atomicAdd(&stats[t], ls[t] + ls[t + DH]);
    atomicAdd(&stats[DH + t], ls2[t] + ls2[t + DH]);
  }
}

// ---- BN apply + ReLU -> bf16 ----
__global__ void k_bnapply(const float* __restrict__ h, const float* __restrict__ stats,
                          const float* __restrict__ g, const float* __restrict__ be,
                          unsigned short* __restrict__ hb) {
  int i = blockIdx.x * blockDim.x + threadIdx.x;
  if (i >= NN * DH / 4) return;
  int c = (i * 4) & (DH - 1);
  float4 v = reinterpret_cast<const float4*>(h)[i];
  float vv[4] = {v.x, v.y, v.z, v.w};
  us4 o;
#pragma unroll
  for (int j = 0; j < 4; ++j) {
    float mu = stats[c + j] * (1.0f / NN);
    float var = stats[DH + c + j] * (1.0f / NN) - mu * mu;
    float rs = rsqrtf(var + 1e-5f);
    float val = (vv[j] - mu) * rs * g[c + j] + be[c + j];
    o[j] = f2bf(fmaxf(val, 0.0f));
  }
  reinterpret_cast<us4*>(hb)[i] = o;
}

extern "C" void kernel_launch(void* const* d_in, const int* in_sizes, int n_in,
                              void* d_out, int out_size, void* d_ws, size_t ws_size,
                              hipStream_t stream) {
  const float* x = (const float*)d_in[0];
  const int* ei = (const int*)d_in[1];
  const int* srcp = ei;
  const int* dstp = ei + NE;
  const float* w1l = (const float*)d_in[2];
  const float* w1r = (const float*)d_in[3];
  const float* b1 = (const float*)d_in[4];
  const float* g1 = (const float*)d_in[5];
  const float* be1 = (const float*)d_in[6];
  const float* w2l = (const float*)d_in[7];
  const float* w2r = (const float*)d_in[8];
  const float* b2 = (const float*)d_in[9];
  const float* g2 = (const float*)d_in[10];
  const float* be2 = (const float*)d_in[11];
  const float* w3l = (const float*)d_in[12];
  const float* w3r = (const float*)d_in[13];
  const float* b3 = (const float*)d_in[14];

  char* ws = (char*)d_ws;
  size_t off = 0;
  auto alloc = [&](size_t bytes) {
    char* p = ws + off;
    off = (off + bytes + 255) & ~(size_t)255;
    return p;
  };
  unsigned short* xb = (unsigned short*)alloc((size_t)NN * DH * 2);
  unsigned short* h1 = (unsigned short*)alloc((size_t)NN * DH * 2);
  unsigned short* h2 = (unsigned short*)alloc((size_t)NN * DH * 2);
  unsigned short* meanb = (unsigned short*)alloc((size_t)NN * DH * 2);
  float* gout = (float*)alloc((size_t)NN * DH * 4);
  unsigned short* w1t = (unsigned short*)alloc(128 * 256 * 2);
  unsigned short* w2t = (unsigned short*)alloc(128 * 256 * 2);
  unsigned short* w3t = (unsigned short*)alloc(64 * 256 * 2);
  int* deg = (int*)alloc(NN * 4);
  int* rowptr = (int*)alloc((NN + 1) * 4);
  int* cursor = (int*)alloc(NN * 4);
  int* adj = (int*)alloc((size_t)NE * 4);
  float* invd = (float*)alloc(NN * 4);
  float* stats = (float*)alloc(2 * DH * 4);
  int* iscan = (int*)alloc(NN * 4);
  int* bsum = (int*)alloc(NB1 * 4);

  // ---- one-time prep ----
  hipMemsetAsync(deg, 0, NN * 4, stream);
  k_cvt_x<<<(NN * DH / 8 + 255) / 256, 256, 0, stream>>>(x, xb, NN * DH / 8);
  k_prep_w<<<128, 256, 0, stream>>>(w1l, w1r, w1t, 128);
  k_prep_w<<<128, 256, 0, stream>>>(w2l, w2r, w2t, 128);
  k_prep_w<<<64, 256, 0, stream>>>(w3l, w3r, w3t, 64);
  k_deg<<<(NE + 255) / 256, 256, 0, stream>>>(dstp, deg);
  k_scan1<<<NB1, 256, 0, stream>>>(deg, iscan, bsum);
  k_scan2<<<1, 256, 0, stream>>>(bsum);
  k_scan3<<<NB1, 256, 0, stream>>>(deg, iscan, bsum, rowptr, cursor, invd);
  k_fill<<<(NE + 255) / 256, 256, 0, stream>>>(srcp, dstp, cursor, adj);

  int agg_blocks = (NN * 64 + 255) / 256;
  int gemm_blocks = (NN + 127) / 128;

  // ---- layer 1 ----
  k_agg<<<agg_blocks, 256, 0, stream>>>(xb, rowptr, adj, invd, meanb);
  k_gemm<128, 2, 2><<<gemm_blocks, 256, 0, stream>>>(meanb, xb, w1t, b1, gout);
  hipMemsetAsync(stats, 0, 2 * DH * 4, stream);
  k_bnstats<<<512, 256, 0, stream>>>(gout, stats);
  k_bnapply<<<(NN * DH / 4 + 255) / 256, 256, 0, stream>>>(gout, stats, g1, be1, h1);

  // ---- layer 2 ----
  k_agg<<<agg_blocks, 256, 0, stream>>>(h1, rowptr, adj, invd, meanb);
  k_gemm<128, 2, 2><<<gemm_blocks, 256, 0, stream>>>(meanb, h1, w2t, b2, gout);
  hipMemsetAsync(stats, 0, 2 * DH * 4, stream);
  k_bnstats<<<512, 256, 0, stream>>>(gout, stats);
  k_bnapply<<<(NN * DH / 4 + 255) / 256, 256, 0, stream>>>(gout, stats, g2, be2, h2);

  // ---- layer 3 ----
  k_agg<<<agg_blocks, 256, 0, stream>>>(h2, rowptr, adj, invd, meanb);
  k_gemm<64, 4, 1><<<gemm_blocks, 256, 0, stream>>>(meanb, h2, w3t, b3, (float*)d_out);
}

// Round 4
// 301.492 us; speedup vs baseline: 28.5831x; 1.1707x over previous
//
#include <hip/hip_runtime.h>
#include <hip/hip_bf16.h>

#define NN 50000
#define NE 800000
#define DH 128
#define NB1 196  // ceil(NN/256)

typedef __attribute__((ext_vector_type(8))) short bf16x8;
typedef __attribute__((ext_vector_type(4))) float f32x4;
typedef __attribute__((ext_vector_type(8))) unsigned short us8;
typedef __attribute__((ext_vector_type(4))) unsigned short us4;

__device__ __forceinline__ unsigned short f2bf(float f) {
  unsigned int u = __builtin_bit_cast(unsigned int, f);
  unsigned int r = (u + 0x7FFFu + ((u >> 16) & 1u)) >> 16;
  return (unsigned short)r;
}
__device__ __forceinline__ float bf2f(unsigned int h16) {
  unsigned int u = h16 << 16;
  return __builtin_bit_cast(float, u);
}

// ---- convert x f32 -> bf16, 8 elems/thread ----
__global__ void k_cvt_x(const float* __restrict__ x, unsigned short* __restrict__ xb, int n8) {
  int i = blockIdx.x * blockDim.x + threadIdx.x;
  if (i >= n8) return;
  const float4* p = reinterpret_cast<const float4*>(x) + (size_t)i * 2;
  float4 a = p[0], b = p[1];
  us8 o;
  o[0] = f2bf(a.x); o[1] = f2bf(a.y); o[2] = f2bf(a.z); o[3] = f2bf(a.w);
  o[4] = f2bf(b.x); o[5] = f2bf(b.y); o[6] = f2bf(b.z); o[7] = f2bf(b.w);
  reinterpret_cast<us8*>(xb)[i] = o;
}

// ---- Wt[c][k] = (k<128 ? wl[k][c] : wr[k-128][c]) bf16, K=256 ----
__global__ void k_prep_w(const float* __restrict__ wl, const float* __restrict__ wr,
                         unsigned short* __restrict__ wt, int dout) {
  int idx = blockIdx.x * blockDim.x + threadIdx.x;
  if (idx >= dout * 256) return;
  int c = idx >> 8, k = idx & 255;
  float v = (k < DH) ? wl[k * dout + c] : wr[(k - DH) * dout + c];
  wt[idx] = f2bf(v);
}

// ---- Wt3[c][k]: c<64 -> w3l[k][c], else w3r[k][c-64]; K=128, 128 cols ----
__global__ void k_prep_w3(const float* __restrict__ w3l, const float* __restrict__ w3r,
                          unsigned short* __restrict__ wt) {
  int idx = blockIdx.x * blockDim.x + threadIdx.x;
  if (idx >= 128 * 128) return;
  int c = idx >> 7, k = idx & 127;
  float v = (c < 64) ? w3l[k * 64 + c] : w3r[k * 64 + (c - 64)];
  wt[idx] = f2bf(v);
}

// ---- CSR build ----
__global__ void k_deg(const int* __restrict__ dst, int* __restrict__ deg) {
  int e = blockIdx.x * blockDim.x + threadIdx.x;
  if (e < NE) atomicAdd(&deg[dst[e]], 1);
}

__global__ void k_scan1(const int* __restrict__ deg, int* __restrict__ iscan,
                        int* __restrict__ bsum) {
  __shared__ int s[256];
  int t = threadIdx.x;
  int i = blockIdx.x * 256 + t;
  int d = (i < NN) ? deg[i] : 0;
  s[t] = d;
  __syncthreads();
  for (int off = 1; off < 256; off <<= 1) {
    int v = (t >= off) ? s[t - off] : 0;
    __syncthreads();
    s[t] += v;
    __syncthreads();
  }
  if (i < NN) iscan[i] = s[t];
  if (t == 255) bsum[blockIdx.x] = s[255];
}

__global__ void k_scan2(int* __restrict__ bsum) {
  __shared__ int s[256];
  int t = threadIdx.x;
  int v = (t < NB1) ? bsum[t] : 0;
  s[t] = v;
  __syncthreads();
  for (int off = 1; off < 256; off <<= 1) {
    int u = (t >= off) ? s[t - off] : 0;
    __syncthreads();
    s[t] += u;
    __syncthreads();
  }
  if (t < NB1) bsum[t] = s[t] - v;
}

__global__ void k_scan3(const int* __restrict__ deg, const int* __restrict__ iscan,
                        const int* __restrict__ bsum, int* __restrict__ rowptr,
                        int* __restrict__ cursor, float* __restrict__ invd) {
  int i = blockIdx.x * 256 + threadIdx.x;
  if (i >= NN) return;
  int d = deg[i];
  int excl = bsum[blockIdx.x] + iscan[i] - d;
  rowptr[i] = excl;
  cursor[i] = excl;
  invd[i] = 1.0f / (float)(d > 0 ? d : 1);
  if (i == 0) rowptr[NN] = NE;
}

__global__ void k_fill(const int* __restrict__ src, const int* __restrict__ dst,
                       int* __restrict__ cursor, int* __restrict__ adj) {
  int e = blockIdx.x * blockDim.x + threadIdx.x;
  if (e < NE) {
    int p = atomicAdd(&cursor[dst[e]], 1);
    adj[p] = src[e];
  }
}

// ---- gather-mean (128 cols): wave/node, 16-lane quarters, 4 edges in flight ----
__global__ __launch_bounds__(256) void k_agg(const unsigned short* __restrict__ h,
                                             const int* __restrict__ rowptr,
                                             const int* __restrict__ adj,
                                             const float* __restrict__ invd,
                                             unsigned short* __restrict__ meanb) {
  int wid = (blockIdx.x * blockDim.x + threadIdx.x) >> 6;
  int lane = threadIdx.x & 63;
  if (wid >= NN) return;
  int lo = rowptr[wid], hi = rowptr[wid + 1];
  int q = lane >> 4;
  int c = (lane & 15) << 3;
  float a[8] = {};
  int e = lo;
#pragma unroll 2
  for (; e + 4 <= hi; e += 4) {
    int s = adj[e + q];
    us8 v = *reinterpret_cast<const us8*>(h + (size_t)s * DH + c);
#pragma unroll
    for (int j = 0; j < 8; ++j) a[j] += bf2f(v[j]);
  }
  if (q < hi - e) {
    int s = adj[e + q];
    us8 v = *reinterpret_cast<const us8*>(h + (size_t)s * DH + c);
#pragma unroll
    for (int j = 0; j < 8; ++j) a[j] += bf2f(v[j]);
  }
#pragma unroll
  for (int j = 0; j < 8; ++j) {
    a[j] += __shfl_xor(a[j], 16);
    a[j] += __shfl_xor(a[j], 32);
  }
  if (q == 0) {
    float iv = invd[wid];
    us8 o;
#pragma unroll
    for (int j = 0; j < 8; ++j) o[j] = f2bf(a[j] * iv);
    *reinterpret_cast<us8*>(meanb + (size_t)wid * DH + c) = o;
  }
}

// ---- layer-3 agg: gather 64 bf16 cols of t3, + tr[n] + b3 -> d_out f32 ----
__global__ __launch_bounds__(256) void k_agg3(const unsigned short* __restrict__ t3,
                                              const int* __restrict__ rowptr,
                                              const int* __restrict__ adj,
                                              const float* __restrict__ invd,
                                              const float* __restrict__ b3,
                                              float* __restrict__ out) {
  int wid = (blockIdx.x * blockDim.x + threadIdx.x) >> 6;
  int lane = threadIdx.x & 63;
  if (wid >= NN) return;
  int lo = rowptr[wid], hi = rowptr[wid + 1];
  int q = lane >> 4;
  int c = (lane & 15) << 2;
  float a[4] = {};
  int e = lo;
#pragma unroll 2
  for (; e + 4 <= hi; e += 4) {
    int s = adj[e + q];
    us4 v = *reinterpret_cast<const us4*>(t3 + (size_t)s * 128 + c);
#pragma unroll
    for (int j = 0; j < 4; ++j) a[j] += bf2f(v[j]);
  }
  if (q < hi - e) {
    int s = adj[e + q];
    us4 v = *reinterpret_cast<const us4*>(t3 + (size_t)s * 128 + c);
#pragma unroll
    for (int j = 0; j < 4; ++j) a[j] += bf2f(v[j]);
  }
#pragma unroll
  for (int j = 0; j < 4; ++j) {
    a[j] += __shfl_xor(a[j], 16);
    a[j] += __shfl_xor(a[j], 32);
  }
  if (q == 0) {
    float iv = invd[wid];
    us4 w = *reinterpret_cast<const us4*>(t3 + (size_t)wid * 128 + 64 + c);
    float4 o;
    o.x = a[0] * iv + bf2f(w[0]) + b3[c + 0];
    o.y = a[1] * iv + bf2f(w[1]) + b3[c + 1];
    o.z = a[2] * iv + bf2f(w[2]) + b3[c + 2];
    o.w = a[3] * iv + bf2f(w[3]) + b3[c + 3];
    *reinterpret_cast<float4*>(out + (size_t)wid * 64 + c) = o;
  }
}

// ---- GEMM: A[N,K]bf16 @ Wt[128,K]^T (+bias) -> bf16 out; optional fused BN stats ----
// BN=128 cols, 4 waves 2x2, TM=TN=64, FM=FN=4.
// SPLIT: K=256, A-row = [Am-row(128) | Ah-row(128)]. else K=128 from Am.
template <bool SPLIT, bool STATS>
__global__ __launch_bounds__(256) void k_gemm(const unsigned short* __restrict__ Am,
                                              const unsigned short* __restrict__ Ah,
                                              const unsigned short* __restrict__ Wt,
                                              const float* __restrict__ bias,
                                              unsigned short* __restrict__ outb,
                                              float* __restrict__ stats) {
  constexpr int KS = SPLIT ? 8 : 4;
  constexpr int WK = KS * 32;  // Wt row length
  int lane = threadIdx.x & 63;
  int w = threadIdx.x >> 6;
  int wr = w >> 1, wc = w & 1;
  int rowbase = blockIdx.x * 128 + wr * 64;
  int colbase = wc * 64;
  int lr = lane & 15, lk = (lane >> 4) << 3;

  f32x4 acc[4][4] = {};
#pragma unroll
  for (int ks = 0; ks < KS; ++ks) {
    const unsigned short* Ab = (!SPLIT || ks < 4) ? Am : Ah;
    int ka = ((ks & 3) << 5) + lk;
    int kw = (ks << 5) + lk;
    bf16x8 af[4], bfr[4];
#pragma unroll
    for (int i = 0; i < 4; ++i) {
      int r = rowbase + i * 16 + lr;
      r = r < NN ? r : NN - 1;
      af[i] = *reinterpret_cast<const bf16x8*>(Ab + (size_t)r * DH + ka);
    }
#pragma unroll
    for (int j = 0; j < 4; ++j)
      bfr[j] = *reinterpret_cast<const bf16x8*>(Wt + (size_t)(colbase + j * 16 + lr) * WK + kw);
#pragma unroll
    for (int i = 0; i < 4; ++i)
#pragma unroll
      for (int j = 0; j < 4; ++j)
        acc[i][j] = __builtin_amdgcn_mfma_f32_16x16x32_bf16(af[i], bfr[j], acc[i][j], 0, 0, 0);
  }

  float bv[4];
#pragma unroll
  for (int j = 0; j < 4; ++j) bv[j] = bias ? bias[colbase + j * 16 + lr] : 0.0f;

  float s1[4] = {}, s2[4] = {};
#pragma unroll
  for (int i = 0; i < 4; ++i) {
#pragma unroll
    for (int j = 0; j < 4; ++j) {
      int col = colbase + j * 16 + lr;
#pragma unroll
      for (int r = 0; r < 4; ++r) {
        int row = rowbase + i * 16 + ((lane >> 4) << 2) + r;
        if (row < NN) {
          float val = acc[i][j][r] + bv[j];
          outb[(size_t)row * 128 + col] = f2bf(val);
          if (STATS) { s1[j] += val; s2[j] += val * val; }
        }
      }
    }
  }

  if (STATS) {
    __shared__ float sd[2][128][2];
#pragma unroll
    for (int j = 0; j < 4; ++j) {
      s1[j] += __shfl_xor(s1[j], 16);
      s1[j] += __shfl_xor(s1[j], 32);
      s2[j] += __shfl_xor(s2[j], 16);
      s2[j] += __shfl_xor(s2[j], 32);
    }
    if (lane < 16) {
#pragma unroll
      for (int j = 0; j < 4; ++j) {
        sd[wr][colbase + j * 16 + lane][0] = s1[j];
        sd[wr][colbase + j * 16 + lane][1] = s2[j];
      }
    }
    __syncthreads();
    int t = threadIdx.x;
    if (t < 128) {
      atomicAdd(&stats[t], sd[0][t][0] + sd[1][t][0]);
      atomicAdd(&stats[128 + t], sd[0][t][1] + sd[1][t][1]);
    }
  }
}

// ---- BN apply + ReLU: bf16 in -> bf16 out ----
__global__ void k_bnapply(const unsigned short* __restrict__ gin, const float* __restrict__ stats,
                          const float* __restrict__ g, const float* __restrict__ be,
                          unsigned short* __restrict__ hb) {
  int i = blockIdx.x * blockDim.x + threadIdx.x;
  if (i >= NN * DH / 8) return;
  int c = (i * 8) & 127;
  us8 v = reinterpret_cast<const us8*>(gin)[i];
  us8 o;
#pragma unroll
  for (int j = 0; j < 8; ++j) {
    int col = c + j;
    float mu = stats[col] * (1.0f / NN);
    float var = stats[128 + col] * (1.0f / NN) - mu * mu;
    float rs = rsqrtf(var + 1e-5f);
    float val = (bf2f(v[j]) - mu) * rs * g[col] + be[col];
    o[j] = f2bf(fmaxf(val, 0.0f));
  }
  reinterpret_cast<us8*>(hb)[i] = o;
}

extern "C" void kernel_launch(void* const* d_in, const int* in_sizes, int n_in,
                              void* d_out, int out_size, void* d_ws, size_t ws_size,
                              hipStream_t stream) {
  const float* x = (const float*)d_in[0];
  const int* ei = (const int*)d_in[1];
  const int* srcp = ei;
  const int* dstp = ei + NE;
  const float* w1l = (const float*)d_in[2];
  const float* w1r = (const float*)d_in[3];
  const float* b1 = (const float*)d_in[4];
  const float* g1 = (const float*)d_in[5];
  const float* be1 = (const float*)d_in[6];
  const float* w2l = (const float*)d_in[7];
  const float* w2r = (const float*)d_in[8];
  const float* b2 = (const float*)d_in[9];
  const float* g2 = (const float*)d_in[10];
  const float* be2 = (const float*)d_in[11];
  const float* w3l = (const float*)d_in[12];
  const float* w3r = (const float*)d_in[13];
  const float* b3 = (const float*)d_in[14];

  char* ws = (char*)d_ws;
  size_t off = 0;
  auto alloc = [&](size_t bytes) {
    char* p = ws + off;
    off = (off + bytes + 255) & ~(size_t)255;
    return p;
  };
  unsigned short* xb = (unsigned short*)alloc((size_t)NN * DH * 2);
  unsigned short* h1 = (unsigned short*)alloc((size_t)NN * DH * 2);
  unsigned short* h2 = (unsigned short*)alloc((size_t)NN * DH * 2);
  unsigned short* meanb = (unsigned short*)alloc((size_t)NN * DH * 2);
  unsigned short* gbuf = (unsigned short*)alloc((size_t)NN * DH * 2);  // gemm out / t3
  unsigned short* w1t = (unsigned short*)alloc(128 * 256 * 2);
  unsigned short* w2t = (unsigned short*)alloc(128 * 256 * 2);
  unsigned short* w3t = (unsigned short*)alloc(128 * 128 * 2);
  int* deg = (int*)alloc(NN * 4);
  int* rowptr = (int*)alloc((NN + 1) * 4);
  int* cursor = (int*)alloc(NN * 4);
  int* adj = (int*)alloc((size_t)NE * 4);
  float* invd = (float*)alloc(NN * 4);
  float* stats1 = (float*)alloc(2 * DH * 4);
  float* stats2 = (float*)alloc(2 * DH * 4);
  int* iscan = (int*)alloc(NN * 4);
  int* bsum = (int*)alloc(NB1 * 4);

  // ---- one-time prep ----
  hipMemsetAsync(deg, 0, NN * 4, stream);
  hipMemsetAsync(stats1, 0, 2 * 2 * DH * 4 + 256, stream);  // stats1+stats2 (adjacent)
  k_cvt_x<<<(NN * DH / 8 + 255) / 256, 256, 0, stream>>>(x, xb, NN * DH / 8);
  k_prep_w<<<128, 256, 0, stream>>>(w1l, w1r, w1t, 128);
  k_prep_w<<<128, 256, 0, stream>>>(w2l, w2r, w2t, 128);
  k_prep_w3<<<64, 256, 0, stream>>>(w3l, w3r, w3t);
  k_deg<<<(NE + 255) / 256, 256, 0, stream>>>(dstp, deg);
  k_scan1<<<NB1, 256, 0, stream>>>(deg, iscan, bsum);
  k_scan2<<<1, 256, 0, stream>>>(bsum);
  k_scan3<<<NB1, 256, 0, stream>>>(deg, iscan, bsum, rowptr, cursor, invd);
  k_fill<<<(NE + 255) / 256, 256, 0, stream>>>(srcp, dstp, cursor, adj);

  int agg_blocks = (NN * 64 + 255) / 256;
  int gemm_blocks = (NN + 127) / 128;

  // ---- layer 1 ----
  k_agg<<<agg_blocks, 256, 0, stream>>>(xb, rowptr, adj, invd, meanb);
  k_gemm<true, true><<<gemm_blocks, 256, 0, stream>>>(meanb, xb, w1t, b1, gbuf, stats1);
  k_bnapply<<<(NN * DH / 8 + 255) / 256, 256, 0, stream>>>(gbuf, stats1, g1, be1, h1);

  // ---- layer 2 ----
  k_agg<<<agg_blocks, 256, 0, stream>>>(h1, rowptr, adj, invd, meanb);
  k_gemm<true, true><<<gemm_blocks, 256, 0, stream>>>(meanb, h1, w2t, b2, gbuf, stats2);
  k_bnapply<<<(NN * DH / 8 + 255) / 256, 256, 0, stream>>>(gbuf, stats2, g2, be2, h2);

  // ---- layer 3: transform-first, then aggregate ----
  k_gemm<false, false><<<gemm_blocks, 256, 0, stream>>>(h2, nullptr, w3t, nullptr, gbuf, nullptr);
  k_agg3<<<agg_blocks, 256, 0, stream>>>(gbuf, rowptr, adj, invd, b3, (float*)d_out);
}

// Round 5
// 269.205 us; speedup vs baseline: 32.0113x; 1.1199x over previous
//
#include <hip/hip_runtime.h>
#include <hip/hip_bf16.h>

#define NN 50000
#define NE 800000
#define DH 128
#define NB1 196   // ceil(NN/256)
#define NBK 391   // ceil(NN/128) buckets for CSR fill
#define EPB 4096  // edges per bucket-scatter workgroup

typedef __attribute__((ext_vector_type(8))) short bf16x8;
typedef __attribute__((ext_vector_type(4))) float f32x4;
typedef __attribute__((ext_vector_type(8))) unsigned short us8;
typedef __attribute__((ext_vector_type(4))) unsigned short us4;

__device__ __forceinline__ unsigned short f2bf(float f) {
  unsigned int u = __builtin_bit_cast(unsigned int, f);
  unsigned int r = (u + 0x7FFFu + ((u >> 16) & 1u)) >> 16;
  return (unsigned short)r;
}
__device__ __forceinline__ float bf2f(unsigned int h16) {
  unsigned int u = h16 << 16;
  return __builtin_bit_cast(float, u);
}

// ---- convert x f32 -> bf16, 8 elems/thread ----
__global__ void k_cvt_x(const float* __restrict__ x, unsigned short* __restrict__ xb, int n8) {
  int i = blockIdx.x * blockDim.x + threadIdx.x;
  if (i >= n8) return;
  const float4* p = reinterpret_cast<const float4*>(x) + (size_t)i * 2;
  float4 a = p[0], b = p[1];
  us8 o;
  o[0] = f2bf(a.x); o[1] = f2bf(a.y); o[2] = f2bf(a.z); o[3] = f2bf(a.w);
  o[4] = f2bf(b.x); o[5] = f2bf(b.y); o[6] = f2bf(b.z); o[7] = f2bf(b.w);
  reinterpret_cast<us8*>(xb)[i] = o;
}

// ---- Wt[c][k] = (k<128 ? wl[k][c] : wr[k-128][c]) bf16, K=256 ----
__global__ void k_prep_w(const float* __restrict__ wl, const float* __restrict__ wr,
                         unsigned short* __restrict__ wt, int dout) {
  int idx = blockIdx.x * blockDim.x + threadIdx.x;
  if (idx >= dout * 256) return;
  int c = idx >> 8, k = idx & 255;
  float v = (k < DH) ? wl[k * dout + c] : wr[(k - DH) * dout + c];
  wt[idx] = f2bf(v);
}

// ---- Wt3[c][k]: c<64 -> w3l[k][c], else w3r[k][c-64]; K=128, 128 cols ----
__global__ void k_prep_w3(const float* __restrict__ w3l, const float* __restrict__ w3r,
                          unsigned short* __restrict__ wt) {
  int idx = blockIdx.x * blockDim.x + threadIdx.x;
  if (idx >= 128 * 128) return;
  int c = idx >> 7, k = idx & 127;
  float v = (c < 64) ? w3l[k * 64 + c] : w3r[k * 64 + (c - 64)];
  wt[idx] = f2bf(v);
}

// ---- CSR build ----
__global__ void k_deg(const int* __restrict__ dst, int* __restrict__ deg) {
  int e = blockIdx.x * blockDim.x + threadIdx.x;
  if (e < NE) atomicAdd(&deg[dst[e]], 1);
}

__global__ void k_scan1(const int* __restrict__ deg, int* __restrict__ iscan,
                        int* __restrict__ bsum) {
  __shared__ int s[256];
  int t = threadIdx.x;
  int i = blockIdx.x * 256 + t;
  int d = (i < NN) ? deg[i] : 0;
  s[t] = d;
  __syncthreads();
  for (int off = 1; off < 256; off <<= 1) {
    int v = (t >= off) ? s[t - off] : 0;
    __syncthreads();
    s[t] += v;
    __syncthreads();
  }
  if (i < NN) iscan[i] = s[t];
  if (t == 255) bsum[blockIdx.x] = s[255];
}

__global__ void k_scan2(int* __restrict__ bsum) {
  __shared__ int s[256];
  int t = threadIdx.x;
  int v = (t < NB1) ? bsum[t] : 0;
  s[t] = v;
  __syncthreads();
  for (int off = 1; off < 256; off <<= 1) {
    int u = (t >= off) ? s[t - off] : 0;
    __syncthreads();
    s[t] += u;
    __syncthreads();
  }
  if (t < NB1) bsum[t] = s[t] - v;
}

// apply block prefixes -> rowptr/invd; init per-bucket cursors at 128-node marks
__global__ void k_scan3(const int* __restrict__ deg, const int* __restrict__ iscan,
                        const int* __restrict__ bsum, int* __restrict__ rowptr,
                        int* __restrict__ bcursor, float* __restrict__ invd) {
  int i = blockIdx.x * 256 + threadIdx.x;
  if (i >= NN) return;
  int d = deg[i];
  int excl = bsum[blockIdx.x] + iscan[i] - d;
  rowptr[i] = excl;
  if ((i & 127) == 0) bcursor[i >> 7] = excl;
  invd[i] = 1.0f / (float)(d > 0 ? d : 1);
  if (i == 0) rowptr[NN] = NE;
}

// ---- bucket scatter: group (src,dst) pairs by dst>>7 with chunk-local LDS ranks ----
__global__ __launch_bounds__(256) void k_bucket(const int* __restrict__ src,
                                                const int* __restrict__ dst,
                                                int* __restrict__ bcursor,
                                                int2* __restrict__ ebuf) {
  __shared__ int lcnt[NBK], lbase[NBK];
  int t = threadIdx.x;
  for (int b = t; b < NBK; b += 256) lcnt[b] = 0;
  __syncthreads();
  int base = blockIdx.x * EPB;
  int d[16], s[16];
#pragma unroll
  for (int i = 0; i < 16; ++i) {
    int e = base + i * 256 + t;
    if (e < NE) { d[i] = dst[e]; s[i] = src[e]; }
    else d[i] = -1;
  }
#pragma unroll
  for (int i = 0; i < 16; ++i)
    if (d[i] >= 0) atomicAdd(&lcnt[d[i] >> 7], 1);
  __syncthreads();
  for (int b = t; b < NBK; b += 256) {
    int c = lcnt[b];
    lbase[b] = c > 0 ? atomicAdd(&bcursor[b], c) : 0;
    lcnt[b] = 0;
  }
  __syncthreads();
#pragma unroll
  for (int i = 0; i < 16; ++i) {
    if (d[i] >= 0) {
      int b = d[i] >> 7;
      int r = atomicAdd(&lcnt[b], 1);
      ebuf[lbase[b] + r] = make_int2(s[i], d[i]);
    }
  }
}

// ---- per-bucket CSR fill: LDS cursors, writes confined to bucket's adj window ----
__global__ __launch_bounds__(256) void k_fill2(const int* __restrict__ rowptr,
                                               const int2* __restrict__ ebuf,
                                               int* __restrict__ adj) {
  int b = blockIdx.x;
  int n0 = b << 7;
  int n1 = n0 + 128; if (n1 > NN) n1 = NN;
  __shared__ int cur[128];
  int t = threadIdx.x;
  if (t < n1 - n0) cur[t] = rowptr[n0 + t];
  __syncthreads();
  int e0 = rowptr[n0], e1 = rowptr[n1];
  for (int e = e0 + t; e < e1; e += 256) {
    int2 pr = ebuf[e];
    int p = atomicAdd(&cur[pr.y - n0], 1);
    adj[p] = pr.x;
  }
}

// ---- gather-mean (128 cols): wave/node, 16-lane quarters, 4 edges in flight ----
__global__ __launch_bounds__(256) void k_agg(const unsigned short* __restrict__ h,
                                             const int* __restrict__ rowptr,
                                             const int* __restrict__ adj,
                                             const float* __restrict__ invd,
                                             unsigned short* __restrict__ meanb) {
  int wid = (blockIdx.x * blockDim.x + threadIdx.x) >> 6;
  int lane = threadIdx.x & 63;
  if (wid >= NN) return;
  int lo = rowptr[wid], hi = rowptr[wid + 1];
  int q = lane >> 4;
  int c = (lane & 15) << 3;
  float a[8] = {};
  int e = lo;
#pragma unroll 2
  for (; e + 4 <= hi; e += 4) {
    int s = adj[e + q];
    us8 v = *reinterpret_cast<const us8*>(h + (size_t)s * DH + c);
#pragma unroll
    for (int j = 0; j < 8; ++j) a[j] += bf2f(v[j]);
  }
  if (q < hi - e) {
    int s = adj[e + q];
    us8 v = *reinterpret_cast<const us8*>(h + (size_t)s * DH + c);
#pragma unroll
    for (int j = 0; j < 8; ++j) a[j] += bf2f(v[j]);
  }
#pragma unroll
  for (int j = 0; j < 8; ++j) {
    a[j] += __shfl_xor(a[j], 16);
    a[j] += __shfl_xor(a[j], 32);
  }
  if (q == 0) {
    float iv = invd[wid];
    us8 o;
#pragma unroll
    for (int j = 0; j < 8; ++j) o[j] = f2bf(a[j] * iv);
    *reinterpret_cast<us8*>(meanb + (size_t)wid * DH + c) = o;
  }
}

// ---- layer-3 agg: gather 64 bf16 cols of t3, + tr[n] + b3 -> d_out f32 ----
__global__ __launch_bounds__(256) void k_agg3(const unsigned short* __restrict__ t3,
                                              const int* __restrict__ rowptr,
                                              const int* __restrict__ adj,
                                              const float* __restrict__ invd,
                                              const float* __restrict__ b3,
                                              float* __restrict__ out) {
  int wid = (blockIdx.x * blockDim.x + threadIdx.x) >> 6;
  int lane = threadIdx.x & 63;
  if (wid >= NN) return;
  int lo = rowptr[wid], hi = rowptr[wid + 1];
  int q = lane >> 4;
  int c = (lane & 15) << 2;
  float a[4] = {};
  int e = lo;
#pragma unroll 2
  for (; e + 4 <= hi; e += 4) {
    int s = adj[e + q];
    us4 v = *reinterpret_cast<const us4*>(t3 + (size_t)s * 128 + c);
#pragma unroll
    for (int j = 0; j < 4; ++j) a[j] += bf2f(v[j]);
  }
  if (q < hi - e) {
    int s = adj[e + q];
    us4 v = *reinterpret_cast<const us4*>(t3 + (size_t)s * 128 + c);
#pragma unroll
    for (int j = 0; j < 4; ++j) a[j] += bf2f(v[j]);
  }
#pragma unroll
  for (int j = 0; j < 4; ++j) {
    a[j] += __shfl_xor(a[j], 16);
    a[j] += __shfl_xor(a[j], 32);
  }
  if (q == 0) {
    float iv = invd[wid];
    us4 w = *reinterpret_cast<const us4*>(t3 + (size_t)wid * 128 + 64 + c);
    float4 o;
    o.x = a[0] * iv + bf2f(w[0]) + b3[c + 0];
    o.y = a[1] * iv + bf2f(w[1]) + b3[c + 1];
    o.z = a[2] * iv + bf2f(w[2]) + b3[c + 2];
    o.w = a[3] * iv + bf2f(w[3]) + b3[c + 3];
    *reinterpret_cast<float4*>(out + (size_t)wid * 64 + c) = o;
  }
}

// ---- GEMM: A[N,K]bf16 @ Wt[128,K]^T (+bias) -> bf16 out; optional fused BN stats ----
template <bool SPLIT, bool STATS>
__global__ __launch_bounds__(256) void k_gemm(const unsigned short* __restrict__ Am,
                                              const unsigned short* __restrict__ Ah,
                                              const unsigned short* __restrict__ Wt,
                                              const float* __restrict__ bias,
                                              unsigned short* __restrict__ outb,
                                              float* __restrict__ stats) {
  constexpr int KS = SPLIT ? 8 : 4;
  constexpr int WK = KS * 32;
  int lane = threadIdx.x & 63;
  int w = threadIdx.x >> 6;
  int wr = w >> 1, wc = w & 1;
  int rowbase = blockIdx.x * 128 + wr * 64;
  int colbase = wc * 64;
  int lr = lane & 15, lk = (lane >> 4) << 3;

  f32x4 acc[4][4] = {};
#pragma unroll
  for (int ks = 0; ks < KS; ++ks) {
    const unsigned short* Ab = (!SPLIT || ks < 4) ? Am : Ah;
    int ka = ((ks & 3) << 5) + lk;
    int kw = (ks << 5) + lk;
    bf16x8 af[4], bfr[4];
#pragma unroll
    for (int i = 0; i < 4; ++i) {
      int r = rowbase + i * 16 + lr;
      r = r < NN ? r : NN - 1;
      af[i] = *reinterpret_cast<const bf16x8*>(Ab + (size_t)r * DH + ka);
    }
#pragma unroll
    for (int j = 0; j < 4; ++j)
      bfr[j] = *reinterpret_cast<const bf16x8*>(Wt + (size_t)(colbase + j * 16 + lr) * WK + kw);
#pragma unroll
    for (int i = 0; i < 4; ++i)
#pragma unroll
      for (int j = 0; j < 4; ++j)
        acc[i][j] = __builtin_amdgcn_mfma_f32_16x16x32_bf16(af[i], bfr[j], acc[i][j], 0, 0, 0);
  }

  float bv[4];
#pragma unroll
  for (int j = 0; j < 4; ++j) bv[j] = bias ? bias[colbase + j * 16 + lr] : 0.0f;

  float s1[4] = {}, s2[4] = {};
#pragma unroll
  for (int i = 0; i < 4; ++i) {
#pragma unroll
    for (int j = 0; j < 4; ++j) {
      int col = colbase + j * 16 + lr;
#pragma unroll
      for (int r = 0; r < 4; ++r) {
        int row = rowbase + i * 16 + ((lane >> 4) << 2) + r;
        if (row < NN) {
          float val = acc[i][j][r] + bv[j];
          outb[(size_t)row * 128 + col] = f2bf(val);
          if (STATS) { s1[j] += val; s2[j] += val * val; }
        }
      }
    }
  }

  if (STATS) {
    __shared__ float sd[2][128][2];
#pragma unroll
    for (int j = 0; j < 4; ++j) {
      s1[j] += __shfl_xor(s1[j], 16);
      s1[j] += __shfl_xor(s1[j], 32);
      s2[j] += __shfl_xor(s2[j], 16);
      s2[j] += __shfl_xor(s2[j], 32);
    }
    if (lane < 16) {
#pragma unroll
      for (int j = 0; j < 4; ++j) {
        sd[wr][colbase + j * 16 + lane][0] = s1[j];
        sd[wr][colbase + j * 16 + lane][1] = s2[j];
      }
    }
    __syncthreads();
    int t = threadIdx.x;
    if (t < 128) {
      atomicAdd(&stats[t], sd[0][t][0] + sd[1][t][0]);
      atomicAdd(&stats[128 + t], sd[0][t][1] + sd[1][t][1]);
    }
  }
}

// ---- BN apply + ReLU: bf16 in -> bf16 out ----
__global__ void k_bnapply(const unsigned short* __restrict__ gin, const float* __restrict__ stats,
                          const float* __restrict__ g, const float* __restrict__ be,
                          unsigned short* __restrict__ hb) {
  int i = blockIdx.x * blockDim.x + threadIdx.x;
  if (i >= NN * DH / 8) return;
  int c = (i * 8) & 127;
  us8 v = reinterpret_cast<const us8*>(gin)[i];
  us8 o;
#pragma unroll
  for (int j = 0; j < 8; ++j) {
    int col = c + j;
    float mu = stats[col] * (1.0f / NN);
    float var = stats[128 + col] * (1.0f / NN) - mu * mu;
    float rs = rsqrtf(var + 1e-5f);
    float val = (bf2f(v[j]) - mu) * rs * g[col] + be[col];
    o[j] = f2bf(fmaxf(val, 0.0f));
  }
  reinterpret_cast<us8*>(hb)[i] = o;
}

extern "C" void kernel_launch(void* const* d_in, const int* in_sizes, int n_in,
                              void* d_out, int out_size, void* d_ws, size_t ws_size,
                              hipStream_t stream) {
  const float* x = (const float*)d_in[0];
  const int* ei = (const int*)d_in[1];
  const int* srcp = ei;
  const int* dstp = ei + NE;
  const float* w1l = (const float*)d_in[2];
  const float* w1r = (const float*)d_in[3];
  const float* b1 = (const float*)d_in[4];
  const float* g1 = (const float*)d_in[5];
  const float* be1 = (const float*)d_in[6];
  const float* w2l = (const float*)d_in[7];
  const float* w2r = (const float*)d_in[8];
  const float* b2 = (const float*)d_in[9];
  const float* g2 = (const float*)d_in[10];
  const float* be2 = (const float*)d_in[11];
  const float* w3l = (const float*)d_in[12];
  const float* w3r = (const float*)d_in[13];
  const float* b3 = (const float*)d_in[14];

  char* ws = (char*)d_ws;
  size_t off = 0;
  auto alloc = [&](size_t bytes) {
    char* p = ws + off;
    off = (off + bytes + 255) & ~(size_t)255;
    return p;
  };
  unsigned short* xb = (unsigned short*)alloc((size_t)NN * DH * 2);
  unsigned short* h1 = (unsigned short*)alloc((size_t)NN * DH * 2);
  unsigned short* h2 = (unsigned short*)alloc((size_t)NN * DH * 2);
  unsigned short* meanb = (unsigned short*)alloc((size_t)NN * DH * 2);
  unsigned short* gbuf = (unsigned short*)alloc((size_t)NN * DH * 2);
  unsigned short* w1t = (unsigned short*)alloc(128 * 256 * 2);
  unsigned short* w2t = (unsigned short*)alloc(128 * 256 * 2);
  unsigned short* w3t = (unsigned short*)alloc(128 * 128 * 2);
  int* deg = (int*)alloc(NN * 4);
  int* rowptr = (int*)alloc((NN + 1) * 4);
  int* adj = (int*)alloc((size_t)NE * 4);
  int2* ebuf = (int2*)alloc((size_t)NE * 8);
  int* bcursor = (int*)alloc(NBK * 4);
  float* invd = (float*)alloc(NN * 4);
  float* stats1 = (float*)alloc(2 * DH * 4);
  float* stats2 = (float*)alloc(2 * DH * 4);
  int* iscan = (int*)alloc(NN * 4);
  int* bsum = (int*)alloc(NB1 * 4);

  // ---- one-time prep ----
  hipMemsetAsync(deg, 0, NN * 4, stream);
  hipMemsetAsync(stats1, 0, 2 * 2 * DH * 4 + 256, stream);
  k_cvt_x<<<(NN * DH / 8 + 255) / 256, 256, 0, stream>>>(x, xb, NN * DH / 8);
  k_prep_w<<<128, 256, 0, stream>>>(w1l, w1r, w1t, 128);
  k_prep_w<<<128, 256, 0, stream>>>(w2l, w2r, w2t, 128);
  k_prep_w3<<<64, 256, 0, stream>>>(w3l, w3r, w3t);
  k_deg<<<(NE + 255) / 256, 256, 0, stream>>>(dstp, deg);
  k_scan1<<<NB1, 256, 0, stream>>>(deg, iscan, bsum);
  k_scan2<<<1, 256, 0, stream>>>(bsum);
  k_scan3<<<NB1, 256, 0, stream>>>(deg, iscan, bsum, rowptr, bcursor, invd);
  k_bucket<<<(NE + EPB - 1) / EPB, 256, 0, stream>>>(srcp, dstp, bcursor, ebuf);
  k_fill2<<<NBK, 256, 0, stream>>>(rowptr, ebuf, adj);

  int agg_blocks = (NN * 64 + 255) / 256;
  int gemm_blocks = (NN + 127) / 128;

  // ---- layer 1 ----
  k_agg<<<agg_blocks, 256, 0, stream>>>(xb, rowptr, adj, invd, meanb);
  k_gemm<true, true><<<gemm_blocks, 256, 0, stream>>>(meanb, xb, w1t, b1, gbuf, stats1);
  k_bnapply<<<(NN * DH / 8 + 255) / 256, 256, 0, stream>>>(gbuf, stats1, g1, be1, h1);

  // ---- layer 2 ----
  k_agg<<<agg_blocks, 256, 0, stream>>>(h1, rowptr, adj, invd, meanb);
  k_gemm<true, true><<<gemm_blocks, 256, 0, stream>>>(meanb, h1, w2t, b2, gbuf, stats2);
  k_bnapply<<<(NN * DH / 8 + 255) / 256, 256, 0, stream>>>(gbuf, stats2, g2, be2, h2);

  // ---- layer 3: transform-first, then aggregate ----
  k_gemm<false, false><<<gemm_blocks, 256, 0, stream>>>(h2, nullptr, w3t, nullptr, gbuf, nullptr);
  k_agg3<<<agg_blocks, 256, 0, stream>>>(gbuf, rowptr, adj, invd, b3, (float*)d_out);
}

// Round 6
// 245.831 us; speedup vs baseline: 35.0549x; 1.0951x over previous
//
#include <hip/hip_runtime.h>
#include <hip/hip_bf16.h>

#define NN 50000
#define NE 800000
#define DH 128
#define NB1 196   // ceil(NN/256)
#define NBK 391   // ceil(NN/128) buckets
#define EPB 4096  // edges per bucket-scatter workgroup
#define CAPB 4096 // fixed bucket capacity (mean 2046, ~45 sigma headroom)

typedef __attribute__((ext_vector_type(8))) short bf16x8;
typedef __attribute__((ext_vector_type(4))) float f32x4;
typedef __attribute__((ext_vector_type(8))) unsigned short us8;
typedef __attribute__((ext_vector_type(4))) unsigned short us4;

__device__ __forceinline__ unsigned short f2bf(float f) {
  unsigned int u = __builtin_bit_cast(unsigned int, f);
  unsigned int r = (u + 0x7FFFu + ((u >> 16) & 1u)) >> 16;
  return (unsigned short)r;
}
__device__ __forceinline__ float bf2f(unsigned int h16) {
  unsigned int u = h16 << 16;
  return __builtin_bit_cast(float, u);
}

// ---- merged prep: cvt x->bf16 (blocks 0..3124), w1t (..3252), w2t (..3380), w3t (..3444)
__global__ __launch_bounds__(256) void k_prep(const float* __restrict__ x,
                                              const float* __restrict__ w1l, const float* __restrict__ w1r,
                                              const float* __restrict__ w2l, const float* __restrict__ w2r,
                                              const float* __restrict__ w3l, const float* __restrict__ w3r,
                                              unsigned short* __restrict__ xb,
                                              unsigned short* __restrict__ w1t,
                                              unsigned short* __restrict__ w2t,
                                              unsigned short* __restrict__ w3t) {
  int b = blockIdx.x, t = threadIdx.x;
  if (b < 3125) {
    int i = b * 256 + t;
    const float4* p = reinterpret_cast<const float4*>(x) + (size_t)i * 2;
    float4 a = p[0], bb = p[1];
    us8 o;
    o[0] = f2bf(a.x); o[1] = f2bf(a.y); o[2] = f2bf(a.z); o[3] = f2bf(a.w);
    o[4] = f2bf(bb.x); o[5] = f2bf(bb.y); o[6] = f2bf(bb.z); o[7] = f2bf(bb.w);
    reinterpret_cast<us8*>(xb)[i] = o;
  } else if (b < 3381) {
    bool is1 = b < 3253;
    int idx = (b - (is1 ? 3125 : 3253)) * 256 + t;
    int c = idx >> 8, k = idx & 255;
    const float* wl = is1 ? w1l : w2l;
    const float* wr = is1 ? w1r : w2r;
    float v = (k < DH) ? wl[k * DH + c] : wr[(k - DH) * DH + c];
    (is1 ? w1t : w2t)[idx] = f2bf(v);
  } else {
    int idx = (b - 3381) * 256 + t;
    int c = idx >> 7, k = idx & 127;
    float v = (c < 64) ? w3l[k * 64 + c] : w3r[k * 64 + (c - 64)];
    w3t[idx] = f2bf(v);
  }
}

// ---- bucket scatter (+deg count): fixed-cap bucket regions, packed (src|dstlow) ----
__global__ __launch_bounds__(256) void k_bucket(const int* __restrict__ src,
                                                const int* __restrict__ dst,
                                                int* __restrict__ deg,
                                                int* __restrict__ bcnt,
                                                int* __restrict__ ebuf) {
  __shared__ int lcnt[NBK], lbase[NBK];
  int t = threadIdx.x;
  for (int b = t; b < NBK; b += 256) lcnt[b] = 0;
  __syncthreads();
  int base = blockIdx.x * EPB;
  int d[16], s[16];
#pragma unroll
  for (int i = 0; i < 16; ++i) {
    int e = base + i * 256 + t;
    if (e < NE) { d[i] = dst[e]; s[i] = src[e]; }
    else d[i] = -1;
  }
#pragma unroll
  for (int i = 0; i < 16; ++i)
    if (d[i] >= 0) {
      atomicAdd(&deg[d[i]], 1);
      atomicAdd(&lcnt[d[i] >> 7], 1);
    }
  __syncthreads();
  for (int b = t; b < NBK; b += 256) {
    int c = lcnt[b];
    lbase[b] = c > 0 ? atomicAdd(&bcnt[b], c) : 0;
    lcnt[b] = 0;
  }
  __syncthreads();
#pragma unroll
  for (int i = 0; i < 16; ++i) {
    if (d[i] >= 0) {
      int b = d[i] >> 7;
      int r = atomicAdd(&lcnt[b], 1);
      ebuf[(size_t)b * CAPB + lbase[b] + r] = s[i] | ((d[i] & 127) << 20);
    }
  }
}

// ---- scans ----
__global__ void k_scan1(const int* __restrict__ deg, int* __restrict__ iscan,
                        int* __restrict__ bsum) {
  __shared__ int s[256];
  int t = threadIdx.x;
  int i = blockIdx.x * 256 + t;
  int d = (i < NN) ? deg[i] : 0;
  s[t] = d;
  __syncthreads();
  for (int off = 1; off < 256; off <<= 1) {
    int v = (t >= off) ? s[t - off] : 0;
    __syncthreads();
    s[t] += v;
    __syncthreads();
  }
  if (i < NN) iscan[i] = s[t];
  if (t == 255) bsum[blockIdx.x] = s[255];
}

__global__ void k_scan2(int* __restrict__ bsum) {
  __shared__ int s[256];
  int t = threadIdx.x;
  int v = (t < NB1) ? bsum[t] : 0;
  s[t] = v;
  __syncthreads();
  for (int off = 1; off < 256; off <<= 1) {
    int u = (t >= off) ? s[t - off] : 0;
    __syncthreads();
    s[t] += u;
    __syncthreads();
  }
  if (t < NB1) bsum[t] = s[t] - v;
}

__global__ void k_scan3(const int* __restrict__ deg, const int* __restrict__ iscan,
                        const int* __restrict__ bsum, int* __restrict__ rowptr,
                        float* __restrict__ invd) {
  int i = blockIdx.x * 256 + threadIdx.x;
  if (i >= NN) return;
  int d = deg[i];
  int excl = bsum[blockIdx.x] + iscan[i] - d;
  rowptr[i] = excl;
  invd[i] = 1.0f / (float)(d > 0 ? d : 1);
  if (i == 0) rowptr[NN] = NE;
}

// ---- per-bucket CSR fill: LDS cursors; reads its fixed-cap ebuf region ----
__global__ __launch_bounds__(256) void k_fill2(const int* __restrict__ rowptr,
                                               const int* __restrict__ bcnt,
                                               const int* __restrict__ ebuf,
                                               int* __restrict__ adj) {
  int b = blockIdx.x;
  int n0 = b << 7;
  int n1 = n0 + 128; if (n1 > NN) n1 = NN;
  __shared__ int cur[128];
  int t = threadIdx.x;
  if (t < n1 - n0) cur[t] = rowptr[n0 + t];
  __syncthreads();
  int cnt = bcnt[b];
  const int* eb = ebuf + (size_t)b * CAPB;
  for (int e = t; e < cnt; e += 256) {
    int p = eb[e];
    int pos = atomicAdd(&cur[(p >> 20) & 127], 1);
    adj[pos] = p & 0xFFFFF;
  }
}

// ---- gather-mean, optional fused BN+ReLU on gathered elements ----
template <bool BNA>
__global__ __launch_bounds__(256) void k_agg(const unsigned short* __restrict__ h,
                                             const int* __restrict__ rowptr,
                                             const int* __restrict__ adj,
                                             const float* __restrict__ invd,
                                             const float* __restrict__ stats,
                                             const float* __restrict__ g,
                                             const float* __restrict__ be,
                                             unsigned short* __restrict__ meanb) {
  int wid = (blockIdx.x * blockDim.x + threadIdx.x) >> 6;
  int lane = threadIdx.x & 63;
  if (wid >= NN) return;
  int lo = rowptr[wid], hi = rowptr[wid + 1];
  int q = lane >> 4;
  int c = (lane & 15) << 3;
  float sc[8], sh[8];
  if (BNA) {
#pragma unroll
    for (int j = 0; j < 8; ++j) {
      int col = c + j;
      float mu = stats[col] * (1.0f / NN);
      float var = stats[128 + col] * (1.0f / NN) - mu * mu;
      float rs = rsqrtf(var + 1e-5f);
      sc[j] = rs * g[col];
      sh[j] = be[col] - mu * sc[j];
    }
  }
  float a[8] = {};
  int e = lo;
#pragma unroll 2
  for (; e + 4 <= hi; e += 4) {
    int s = adj[e + q];
    us8 v = *reinterpret_cast<const us8*>(h + (size_t)s * DH + c);
#pragma unroll
    for (int j = 0; j < 8; ++j) {
      float f = bf2f(v[j]);
      a[j] += BNA ? fmaxf(f * sc[j] + sh[j], 0.0f) : f;
    }
  }
  if (q < hi - e) {
    int s = adj[e + q];
    us8 v = *reinterpret_cast<const us8*>(h + (size_t)s * DH + c);
#pragma unroll
    for (int j = 0; j < 8; ++j) {
      float f = bf2f(v[j]);
      a[j] += BNA ? fmaxf(f * sc[j] + sh[j], 0.0f) : f;
    }
  }
#pragma unroll
  for (int j = 0; j < 8; ++j) {
    a[j] += __shfl_xor(a[j], 16);
    a[j] += __shfl_xor(a[j], 32);
  }
  if (q == 0) {
    float iv = invd[wid];
    us8 o;
#pragma unroll
    for (int j = 0; j < 8; ++j) o[j] = f2bf(a[j] * iv);
    *reinterpret_cast<us8*>(meanb + (size_t)wid * DH + c) = o;
  }
}

// ---- layer-3 agg: gather 64 bf16 cols of t3, + tr[n] + b3 -> d_out f32 ----
__global__ __launch_bounds__(256) void k_agg3(const unsigned short* __restrict__ t3,
                                              const int* __restrict__ rowptr,
                                              const int* __restrict__ adj,
                                              const float* __restrict__ invd,
                                              const float* __restrict__ b3,
                                              float* __restrict__ out) {
  int wid = (blockIdx.x * blockDim.x + threadIdx.x) >> 6;
  int lane = threadIdx.x & 63;
  if (wid >= NN) return;
  int lo = rowptr[wid], hi = rowptr[wid + 1];
  int q = lane >> 4;
  int c = (lane & 15) << 2;
  float a[4] = {};
  int e = lo;
#pragma unroll 2
  for (; e + 4 <= hi; e += 4) {
    int s = adj[e + q];
    us4 v = *reinterpret_cast<const us4*>(t3 + (size_t)s * 128 + c);
#pragma unroll
    for (int j = 0; j < 4; ++j) a[j] += bf2f(v[j]);
  }
  if (q < hi - e) {
    int s = adj[e + q];
    us4 v = *reinterpret_cast<const us4*>(t3 + (size_t)s * 128 + c);
#pragma unroll
    for (int j = 0; j < 4; ++j) a[j] += bf2f(v[j]);
  }
#pragma unroll
  for (int j = 0; j < 4; ++j) {
    a[j] += __shfl_xor(a[j], 16);
    a[j] += __shfl_xor(a[j], 32);
  }
  if (q == 0) {
    float iv = invd[wid];
    us4 w = *reinterpret_cast<const us4*>(t3 + (size_t)wid * 128 + 64 + c);
    float4 o;
    o.x = a[0] * iv + bf2f(w[0]) + b3[c + 0];
    o.y = a[1] * iv + bf2f(w[1]) + b3[c + 1];
    o.z = a[2] * iv + bf2f(w[2]) + b3[c + 2];
    o.w = a[3] * iv + bf2f(w[3]) + b3[c + 3];
    *reinterpret_cast<float4*>(out + (size_t)wid * 64 + c) = o;
  }
}

// ---- GEMM with optional fused BN+ReLU on the raw-gemm-out A operand ----
// SPLIT: K=256, A = [Am(128) | Ah(128)]; transform applies to Ah.
// !SPLIT: K=128, A = Am; transform applies to Am (when APPLY).
template <bool SPLIT, bool STATS, bool APPLY>
__global__ __launch_bounds__(256) void k_gemm(const unsigned short* __restrict__ Am,
                                              const unsigned short* __restrict__ Ah,
                                              const unsigned short* __restrict__ Wt,
                                              const float* __restrict__ bias,
                                              const float* __restrict__ stA,
                                              const float* __restrict__ gA,
                                              const float* __restrict__ beA,
                                              unsigned short* __restrict__ outb,
                                              float* __restrict__ stats) {
  constexpr int KS = SPLIT ? 8 : 4;
  constexpr int WK = KS * 32;
  __shared__ float asc[DH], ash[DH];
  if (APPLY) {
    int t = threadIdx.x;
    if (t < DH) {
      float mu = stA[t] * (1.0f / NN);
      float var = stA[128 + t] * (1.0f / NN) - mu * mu;
      float rs = rsqrtf(var + 1e-5f);
      float scv = rs * gA[t];
      asc[t] = scv;
      ash[t] = beA[t] - mu * scv;
    }
    __syncthreads();
  }
  int lane = threadIdx.x & 63;
  int w = threadIdx.x >> 6;
  int wr = w >> 1, wc = w & 1;
  int rowbase = blockIdx.x * 128 + wr * 64;
  int colbase = wc * 64;
  int lr = lane & 15, lk = (lane >> 4) << 3;

  f32x4 acc[4][4] = {};
#pragma unroll
  for (int ks = 0; ks < KS; ++ks) {
    const unsigned short* Ab = (!SPLIT || ks < 4) ? Am : Ah;
    bool tr = APPLY && (!SPLIT || ks >= 4);
    int ka = ((ks & 3) << 5) + lk;
    int kw = (ks << 5) + lk;
    bf16x8 af[4], bfr[4];
#pragma unroll
    for (int i = 0; i < 4; ++i) {
      int r = rowbase + i * 16 + lr;
      r = r < NN ? r : NN - 1;
      us8 raw = *reinterpret_cast<const us8*>(Ab + (size_t)r * DH + ka);
      if (tr) {
        us8 o;
#pragma unroll
        for (int j = 0; j < 8; ++j) {
          float f = bf2f(raw[j]);
          o[j] = f2bf(fmaxf(f * asc[ka + j] + ash[ka + j], 0.0f));
        }
        af[i] = __builtin_bit_cast(bf16x8, o);
      } else {
        af[i] = __builtin_bit_cast(bf16x8, raw);
      }
    }
#pragma unroll
    for (int j = 0; j < 4; ++j)
      bfr[j] = *reinterpret_cast<const bf16x8*>(Wt + (size_t)(colbase + j * 16 + lr) * WK + kw);
#pragma unroll
    for (int i = 0; i < 4; ++i)
#pragma unroll
      for (int j = 0; j < 4; ++j)
        acc[i][j] = __builtin_amdgcn_mfma_f32_16x16x32_bf16(af[i], bfr[j], acc[i][j], 0, 0, 0);
  }

  float bv[4];
#pragma unroll
  for (int j = 0; j < 4; ++j) bv[j] = bias ? bias[colbase + j * 16 + lr] : 0.0f;

  float s1[4] = {}, s2[4] = {};
#pragma unroll
  for (int i = 0; i < 4; ++i) {
#pragma unroll
    for (int j = 0; j < 4; ++j) {
      int col = colbase + j * 16 + lr;
#pragma unroll
      for (int r = 0; r < 4; ++r) {
        int row = rowbase + i * 16 + ((lane >> 4) << 2) + r;
        if (row < NN) {
          float val = acc[i][j][r] + bv[j];
          outb[(size_t)row * 128 + col] = f2bf(val);
          if (STATS) { s1[j] += val; s2[j] += val * val; }
        }
      }
    }
  }

  if (STATS) {
    __shared__ float sd[2][128][2];
#pragma unroll
    for (int j = 0; j < 4; ++j) {
      s1[j] += __shfl_xor(s1[j], 16);
      s1[j] += __shfl_xor(s1[j], 32);
      s2[j] += __shfl_xor(s2[j], 16);
      s2[j] += __shfl_xor(s2[j], 32);
    }
    if (lane < 16) {
#pragma unroll
      for (int j = 0; j < 4; ++j) {
        sd[wr][colbase + j * 16 + lane][0] = s1[j];
        sd[wr][colbase + j * 16 + lane][1] = s2[j];
      }
    }
    __syncthreads();
    int t = threadIdx.x;
    if (t < 128) {
      atomicAdd(&stats[t], sd[0][t][0] + sd[1][t][0]);
      atomicAdd(&stats[128 + t], sd[0][t][1] + sd[1][t][1]);
    }
  }
}

extern "C" void kernel_launch(void* const* d_in, const int* in_sizes, int n_in,
                              void* d_out, int out_size, void* d_ws, size_t ws_size,
                              hipStream_t stream) {
  const float* x = (const float*)d_in[0];
  const int* ei = (const int*)d_in[1];
  const int* srcp = ei;
  const int* dstp = ei + NE;
  const float* w1l = (const float*)d_in[2];
  const float* w1r = (const float*)d_in[3];
  const float* b1 = (const float*)d_in[4];
  const float* g1 = (const float*)d_in[5];
  const float* be1 = (const float*)d_in[6];
  const float* w2l = (const float*)d_in[7];
  const float* w2r = (const float*)d_in[8];
  const float* b2 = (const float*)d_in[9];
  const float* g2 = (const float*)d_in[10];
  const float* be2 = (const float*)d_in[11];
  const float* w3l = (const float*)d_in[12];
  const float* w3r = (const float*)d_in[13];
  const float* b3 = (const float*)d_in[14];

  char* ws = (char*)d_ws;
  size_t off = 0;
  auto alloc = [&](size_t bytes) {
    char* p = ws + off;
    off = (off + bytes + 255) & ~(size_t)255;
    return p;
  };
  unsigned short* xb = (unsigned short*)alloc((size_t)NN * DH * 2);
  unsigned short* meanb = (unsigned short*)alloc((size_t)NN * DH * 2);
  unsigned short* gbuf1 = (unsigned short*)alloc((size_t)NN * DH * 2);
  unsigned short* gbuf2 = (unsigned short*)alloc((size_t)NN * DH * 2);
  unsigned short* w1t = (unsigned short*)alloc(128 * 256 * 2);
  unsigned short* w2t = (unsigned short*)alloc(128 * 256 * 2);
  unsigned short* w3t = (unsigned short*)alloc(128 * 128 * 2);
  // zero region: deg | bcnt | stats1 | stats2 (contiguous)
  int* deg = (int*)alloc(NN * 4);
  int* bcnt = (int*)alloc(NBK * 4);
  float* stats1 = (float*)alloc(2 * DH * 4);
  float* stats2 = (float*)alloc(2 * DH * 4);
  size_t zlen = (char*)(stats2 + 2 * DH) - (char*)deg;
  int* rowptr = (int*)alloc((NN + 1) * 4);
  int* adj = (int*)alloc((size_t)NE * 4);
  int* ebuf = (int*)alloc((size_t)NBK * CAPB * 4);
  float* invd = (float*)alloc(NN * 4);
  int* iscan = (int*)alloc(NN * 4);
  int* bsum = (int*)alloc(NB1 * 4);

  // ---- prep ----
  hipMemsetAsync(deg, 0, zlen, stream);
  k_prep<<<3445, 256, 0, stream>>>(x, w1l, w1r, w2l, w2r, w3l, w3r, xb, w1t, w2t, w3t);
  k_bucket<<<(NE + EPB - 1) / EPB, 256, 0, stream>>>(srcp, dstp, deg, bcnt, ebuf);
  k_scan1<<<NB1, 256, 0, stream>>>(deg, iscan, bsum);
  k_scan2<<<1, 256, 0, stream>>>(bsum);
  k_scan3<<<NB1, 256, 0, stream>>>(deg, iscan, bsum, rowptr, invd);
  k_fill2<<<NBK, 256, 0, stream>>>(rowptr, bcnt, ebuf, adj);

  int agg_blocks = (NN * 64 + 255) / 256;
  int gemm_blocks = (NN + 127) / 128;

  // ---- layer 1 ----
  k_agg<false><<<agg_blocks, 256, 0, stream>>>(xb, rowptr, adj, invd, nullptr, nullptr, nullptr, meanb);
  k_gemm<true, true, false><<<gemm_blocks, 256, 0, stream>>>(
      meanb, xb, w1t, b1, nullptr, nullptr, nullptr, gbuf1, stats1);

  // ---- layer 2 (BN1+ReLU fused into agg and gemm A-load) ----
  k_agg<true><<<agg_blocks, 256, 0, stream>>>(gbuf1, rowptr, adj, invd, stats1, g1, be1, meanb);
  k_gemm<true, true, true><<<gemm_blocks, 256, 0, stream>>>(
      meanb, gbuf1, w2t, b2, stats1, g1, be1, gbuf2, stats2);

  // ---- layer 3: transform-first (BN2+ReLU fused into gemm A-load), then aggregate ----
  k_gemm<false, false, true><<<gemm_blocks, 256, 0, stream>>>(
      gbuf2, nullptr, w3t, nullptr, stats2, g2, be2, gbuf1, nullptr);
  k_agg3<<<agg_blocks, 256, 0, stream>>>(gbuf1, rowptr, adj, invd, b3, (float*)d_out);
}

// Round 7
// 221.822 us; speedup vs baseline: 38.8491x; 1.1082x over previous
//
#include <hip/hip_runtime.h>
#include <hip/hip_bf16.h>

#define NN 50000
#define NE 800000
#define DH 128
#define NB1 196   // ceil(NN/256)
#define NBK 391   // ceil(NN/128) buckets
#define EPB 2048  // edges per bucket-scatter workgroup
#define CAPB 4096 // fixed bucket capacity (mean 2046, ~45 sigma headroom)

typedef __attribute__((ext_vector_type(8))) short bf16x8;
typedef __attribute__((ext_vector_type(4))) float f32x4;
typedef __attribute__((ext_vector_type(8))) unsigned short us8;
typedef __attribute__((ext_vector_type(4))) unsigned short us4;

__device__ __forceinline__ unsigned short f2bf(float f) {
  unsigned int u = __builtin_bit_cast(unsigned int, f);
  unsigned int r = (u + 0x7FFFu + ((u >> 16) & 1u)) >> 16;
  return (unsigned short)r;
}
__device__ __forceinline__ float bf2f(unsigned int h16) {
  unsigned int u = h16 << 16;
  return __builtin_bit_cast(float, u);
}

// ---- merged prep: cvt x->bf16 (blocks 0..3124), w1t (..3252), w2t (..3380), w3t (..3444)
__global__ __launch_bounds__(256) void k_prep(const float* __restrict__ x,
                                              const float* __restrict__ w1l, const float* __restrict__ w1r,
                                              const float* __restrict__ w2l, const float* __restrict__ w2r,
                                              const float* __restrict__ w3l, const float* __restrict__ w3r,
                                              unsigned short* __restrict__ xb,
                                              unsigned short* __restrict__ w1t,
                                              unsigned short* __restrict__ w2t,
                                              unsigned short* __restrict__ w3t) {
  int b = blockIdx.x, t = threadIdx.x;
  if (b < 3125) {
    int i = b * 256 + t;
    const float4* p = reinterpret_cast<const float4*>(x) + (size_t)i * 2;
    float4 a = p[0], bb = p[1];
    us8 o;
    o[0] = f2bf(a.x); o[1] = f2bf(a.y); o[2] = f2bf(a.z); o[3] = f2bf(a.w);
    o[4] = f2bf(bb.x); o[5] = f2bf(bb.y); o[6] = f2bf(bb.z); o[7] = f2bf(bb.w);
    reinterpret_cast<us8*>(xb)[i] = o;
  } else if (b < 3381) {
    bool is1 = b < 3253;
    int idx = (b - (is1 ? 3125 : 3253)) * 256 + t;
    int c = idx >> 8, k = idx & 255;
    const float* wl = is1 ? w1l : w2l;
    const float* wr = is1 ? w1r : w2r;
    float v = (k < DH) ? wl[k * DH + c] : wr[(k - DH) * DH + c];
    (is1 ? w1t : w2t)[idx] = f2bf(v);
  } else {
    int idx = (b - 3381) * 256 + t;
    int c = idx >> 7, k = idx & 127;
    float v = (c < 64) ? w3l[k * 64 + c] : w3r[k * 64 + (c - 64)];
    w3t[idx] = f2bf(v);
  }
}

// ---- bucket scatter: fixed-cap bucket regions, packed (src|dstlow); NO deg atomics ----
__global__ __launch_bounds__(256) void k_bucket(const int* __restrict__ src,
                                                const int* __restrict__ dst,
                                                int* __restrict__ bcnt,
                                                int* __restrict__ ebuf) {
  __shared__ int lcnt[NBK], lbase[NBK];
  int t = threadIdx.x;
  for (int b = t; b < NBK; b += 256) lcnt[b] = 0;
  __syncthreads();
  int base = blockIdx.x * EPB;
  int d[8], s[8];
#pragma unroll
  for (int i = 0; i < 8; ++i) {
    int e = base + i * 256 + t;
    if (e < NE) { d[i] = dst[e]; s[i] = src[e]; }
    else d[i] = -1;
  }
#pragma unroll
  for (int i = 0; i < 8; ++i)
    if (d[i] >= 0) atomicAdd(&lcnt[d[i] >> 7], 1);
  __syncthreads();
  for (int b = t; b < NBK; b += 256) {
    int c = lcnt[b];
    lbase[b] = c > 0 ? atomicAdd(&bcnt[b], c) : 0;
    lcnt[b] = 0;
  }
  __syncthreads();
#pragma unroll
  for (int i = 0; i < 8; ++i) {
    if (d[i] >= 0) {
      int b = d[i] >> 7;
      int r = atomicAdd(&lcnt[b], 1);
      ebuf[(size_t)b * CAPB + lbase[b] + r] = s[i] | ((d[i] & 127) << 20);
    }
  }
}

// ---- per-bucket degree histogram -> deg, invd (no global atomics) ----
__global__ __launch_bounds__(256) void k_hist(const int* __restrict__ bcnt,
                                              const int* __restrict__ ebuf,
                                              int* __restrict__ deg,
                                              float* __restrict__ invd) {
  int b = blockIdx.x;
  __shared__ int h[128];
  int t = threadIdx.x;
  if (t < 128) h[t] = 0;
  __syncthreads();
  int cnt = bcnt[b];
  const int* eb = ebuf + (size_t)b * CAPB;
  for (int e = t; e < cnt; e += 256)
    atomicAdd(&h[(eb[e] >> 20) & 127], 1);
  __syncthreads();
  int i = (b << 7) + t;
  if (t < 128 && i < NN) {
    int d = h[t];
    deg[i] = d;
    invd[i] = 1.0f / (float)(d > 0 ? d : 1);
  }
}

// ---- scans ----
__global__ void k_scan1(const int* __restrict__ deg, int* __restrict__ iscan,
                        int* __restrict__ bsum) {
  __shared__ int s[256];
  int t = threadIdx.x;
  int i = blockIdx.x * 256 + t;
  int d = (i < NN) ? deg[i] : 0;
  s[t] = d;
  __syncthreads();
  for (int off = 1; off < 256; off <<= 1) {
    int v = (t >= off) ? s[t - off] : 0;
    __syncthreads();
    s[t] += v;
    __syncthreads();
  }
  if (i < NN) iscan[i] = s[t];
  if (t == 255) bsum[blockIdx.x] = s[255];
}

__global__ void k_scan2(int* __restrict__ bsum) {
  __shared__ int s[256];
  int t = threadIdx.x;
  int v = (t < NB1) ? bsum[t] : 0;
  s[t] = v;
  __syncthreads();
  for (int off = 1; off < 256; off <<= 1) {
    int u = (t >= off) ? s[t - off] : 0;
    __syncthreads();
    s[t] += u;
    __syncthreads();
  }
  if (t < NB1) bsum[t] = s[t] - v;
}

__global__ void k_scan3(const int* __restrict__ deg, const int* __restrict__ iscan,
                        const int* __restrict__ bsum, int* __restrict__ rowptr) {
  int i = blockIdx.x * 256 + threadIdx.x;
  if (i >= NN) return;
  int excl = bsum[blockIdx.x] + iscan[i] - deg[i];
  rowptr[i] = excl;
  if (i == 0) rowptr[NN] = NE;
}

// ---- per-bucket CSR fill: LDS cursors; reads its fixed-cap ebuf region ----
__global__ __launch_bounds__(256) void k_fill2(const int* __restrict__ rowptr,
                                               const int* __restrict__ bcnt,
                                               const int* __restrict__ ebuf,
                                               int* __restrict__ adj) {
  int b = blockIdx.x;
  int n0 = b << 7;
  int n1 = n0 + 128; if (n1 > NN) n1 = NN;
  __shared__ int cur[128];
  int t = threadIdx.x;
  if (t < n1 - n0) cur[t] = rowptr[n0 + t];
  __syncthreads();
  int cnt = bcnt[b];
  const int* eb = ebuf + (size_t)b * CAPB;
  for (int e = t; e < cnt; e += 256) {
    int p = eb[e];
    int pos = atomicAdd(&cur[(p >> 20) & 127], 1);
    adj[pos] = p & 0xFFFFF;
  }
}

// ---- gather-mean, optional fused BN+ReLU on gathered elements ----
template <bool BNA>
__global__ __launch_bounds__(256) void k_agg(const unsigned short* __restrict__ h,
                                             const int* __restrict__ rowptr,
                                             const int* __restrict__ adj,
                                             const float* __restrict__ invd,
                                             const float* __restrict__ stats,
                                             const float* __restrict__ g,
                                             const float* __restrict__ be,
                                             unsigned short* __restrict__ meanb) {
  int wid = (blockIdx.x * blockDim.x + threadIdx.x) >> 6;
  int lane = threadIdx.x & 63;
  if (wid >= NN) return;
  int lo = rowptr[wid], hi = rowptr[wid + 1];
  int q = lane >> 4;
  int c = (lane & 15) << 3;
  float sc[8], sh[8];
  if (BNA) {
#pragma unroll
    for (int j = 0; j < 8; ++j) {
      int col = c + j;
      float mu = stats[col] * (1.0f / NN);
      float var = stats[128 + col] * (1.0f / NN) - mu * mu;
      float rs = rsqrtf(var + 1e-5f);
      sc[j] = rs * g[col];
      sh[j] = be[col] - mu * sc[j];
    }
  }
  float a[8] = {};
  int e = lo;
#pragma unroll 2
  for (; e + 4 <= hi; e += 4) {
    int s = adj[e + q];
    us8 v = *reinterpret_cast<const us8*>(h + (size_t)s * DH + c);
#pragma unroll
    for (int j = 0; j < 8; ++j) {
      float f = bf2f(v[j]);
      a[j] += BNA ? fmaxf(f * sc[j] + sh[j], 0.0f) : f;
    }
  }
  if (q < hi - e) {
    int s = adj[e + q];
    us8 v = *reinterpret_cast<const us8*>(h + (size_t)s * DH + c);
#pragma unroll
    for (int j = 0; j < 8; ++j) {
      float f = bf2f(v[j]);
      a[j] += BNA ? fmaxf(f * sc[j] + sh[j], 0.0f) : f;
    }
  }
#pragma unroll
  for (int j = 0; j < 8; ++j) {
    a[j] += __shfl_xor(a[j], 16);
    a[j] += __shfl_xor(a[j], 32);
  }
  if (q == 0) {
    float iv = invd[wid];
    us8 o;
#pragma unroll
    for (int j = 0; j < 8; ++j) o[j] = f2bf(a[j] * iv);
    *reinterpret_cast<us8*>(meanb + (size_t)wid * DH + c) = o;
  }
}

// ---- layer-3 agg: gather 64 bf16 cols of t3, + tr[n] + b3 -> d_out f32 ----
__global__ __launch_bounds__(256) void k_agg3(const unsigned short* __restrict__ t3,
                                              const int* __restrict__ rowptr,
                                              const int* __restrict__ adj,
                                              const float* __restrict__ invd,
                                              const float* __restrict__ b3,
                                              float* __restrict__ out) {
  int wid = (blockIdx.x * blockDim.x + threadIdx.x) >> 6;
  int lane = threadIdx.x & 63;
  if (wid >= NN) return;
  int lo = rowptr[wid], hi = rowptr[wid + 1];
  int q = lane >> 4;
  int c = (lane & 15) << 2;
  float a[4] = {};
  int e = lo;
#pragma unroll 2
  for (; e + 4 <= hi; e += 4) {
    int s = adj[e + q];
    us4 v = *reinterpret_cast<const us4*>(t3 + (size_t)s * 128 + c);
#pragma unroll
    for (int j = 0; j < 4; ++j) a[j] += bf2f(v[j]);
  }
  if (q < hi - e) {
    int s = adj[e + q];
    us4 v = *reinterpret_cast<const us4*>(t3 + (size_t)s * 128 + c);
#pragma unroll
    for (int j = 0; j < 4; ++j) a[j] += bf2f(v[j]);
  }
#pragma unroll
  for (int j = 0; j < 4; ++j) {
    a[j] += __shfl_xor(a[j], 16);
    a[j] += __shfl_xor(a[j], 32);
  }
  if (q == 0) {
    float iv = invd[wid];
    us4 w = *reinterpret_cast<const us4*>(t3 + (size_t)wid * 128 + 64 + c);
    float4 o;
    o.x = a[0] * iv + bf2f(w[0]) + b3[c + 0];
    o.y = a[1] * iv + bf2f(w[1]) + b3[c + 1];
    o.z = a[2] * iv + bf2f(w[2]) + b3[c + 2];
    o.w = a[3] * iv + bf2f(w[3]) + b3[c + 3];
    *reinterpret_cast<float4*>(out + (size_t)wid * 64 + c) = o;
  }
}

// ---- GEMM with optional fused BN+ReLU on the raw-gemm-out A operand ----
template <bool SPLIT, bool STATS, bool APPLY>
__global__ __launch_bounds__(256) void k_gemm(const unsigned short* __restrict__ Am,
                                              const unsigned short* __restrict__ Ah,
                                              const unsigned short* __restrict__ Wt,
                                              const float* __restrict__ bias,
                                              const float* __restrict__ stA,
                                              const float* __restrict__ gA,
                                              const float* __restrict__ beA,
                                              unsigned short* __restrict__ outb,
                                              float* __restrict__ stats) {
  constexpr int KS = SPLIT ? 8 : 4;
  constexpr int WK = KS * 32;
  __shared__ float asc[DH], ash[DH];
  if (APPLY) {
    int t = threadIdx.x;
    if (t < DH) {
      float mu = stA[t] * (1.0f / NN);
      float var = stA[128 + t] * (1.0f / NN) - mu * mu;
      float rs = rsqrtf(var + 1e-5f);
      float scv = rs * gA[t];
      asc[t] = scv;
      ash[t] = beA[t] - mu * scv;
    }
    __syncthreads();
  }
  int lane = threadIdx.x & 63;
  int w = threadIdx.x >> 6;
  int wr = w >> 1, wc = w & 1;
  int rowbase = blockIdx.x * 128 + wr * 64;
  int colbase = wc * 64;
  int lr = lane & 15, lk = (lane >> 4) << 3;

  f32x4 acc[4][4] = {};
#pragma unroll
  for (int ks = 0; ks < KS; ++ks) {
    const unsigned short* Ab = (!SPLIT || ks < 4) ? Am : Ah;
    bool tr = APPLY && (!SPLIT || ks >= 4);
    int ka = ((ks & 3) << 5) + lk;
    int kw = (ks << 5) + lk;
    bf16x8 af[4], bfr[4];
#pragma unroll
    for (int i = 0; i < 4; ++i) {
      int r = rowbase + i * 16 + lr;
      r = r < NN ? r : NN - 1;
      us8 raw = *reinterpret_cast<const us8*>(Ab + (size_t)r * DH + ka);
      if (tr) {
        us8 o;
#pragma unroll
        for (int j = 0; j < 8; ++j) {
          float f = bf2f(raw[j]);
          o[j] = f2bf(fmaxf(f * asc[ka + j] + ash[ka + j], 0.0f));
        }
        af[i] = __builtin_bit_cast(bf16x8, o);
      } else {
        af[i] = __builtin_bit_cast(bf16x8, raw);
      }
    }
#pragma unroll
    for (int j = 0; j < 4; ++j)
      bfr[j] = *reinterpret_cast<const bf16x8*>(Wt + (size_t)(colbase + j * 16 + lr) * WK + kw);
#pragma unroll
    for (int i = 0; i < 4; ++i)
#pragma unroll
      for (int j = 0; j < 4; ++j)
        acc[i][j] = __builtin_amdgcn_mfma_f32_16x16x32_bf16(af[i], bfr[j], acc[i][j], 0, 0, 0);
  }

  float bv[4];
#pragma unroll
  for (int j = 0; j < 4; ++j) bv[j] = bias ? bias[colbase + j * 16 + lr] : 0.0f;

  float s1[4] = {}, s2[4] = {};
#pragma unroll
  for (int i = 0; i < 4; ++i) {
#pragma unroll
    for (int j = 0; j < 4; ++j) {
      int col = colbase + j * 16 + lr;
#pragma unroll
      for (int r = 0; r < 4; ++r) {
        int row = rowbase + i * 16 + ((lane >> 4) << 2) + r;
        if (row < NN) {
          float val = acc[i][j][r] + bv[j];
          outb[(size_t)row * 128 + col] = f2bf(val);
          if (STATS) { s1[j] += val; s2[j] += val * val; }
        }
      }
    }
  }

  if (STATS) {
    __shared__ float sd[2][128][2];
#pragma unroll
    for (int j = 0; j < 4; ++j) {
      s1[j] += __shfl_xor(s1[j], 16);
      s1[j] += __shfl_xor(s1[j], 32);
      s2[j] += __shfl_xor(s2[j], 16);
      s2[j] += __shfl_xor(s2[j], 32);
    }
    if (lane < 16) {
#pragma unroll
      for (int j = 0; j < 4; ++j) {
        sd[wr][colbase + j * 16 + lane][0] = s1[j];
        sd[wr][colbase + j * 16 + lane][1] = s2[j];
      }
    }
    __syncthreads();
    int t = threadIdx.x;
    if (t < 128) {
      atomicAdd(&stats[t], sd[0][t][0] + sd[1][t][0]);
      atomicAdd(&stats[128 + t], sd[0][t][1] + sd[1][t][1]);
    }
  }
}

extern "C" void kernel_launch(void* const* d_in, const int* in_sizes, int n_in,
                              void* d_out, int out_size, void* d_ws, size_t ws_size,
                              hipStream_t stream) {
  const float* x = (const float*)d_in[0];
  const int* ei = (const int*)d_in[1];
  const int* srcp = ei;
  const int* dstp = ei + NE;
  const float* w1l = (const float*)d_in[2];
  const float* w1r = (const float*)d_in[3];
  const float* b1 = (const float*)d_in[4];
  const float* g1 = (const float*)d_in[5];
  const float* be1 = (const float*)d_in[6];
  const float* w2l = (const float*)d_in[7];
  const float* w2r = (const float*)d_in[8];
  const float* b2 = (const float*)d_in[9];
  const float* g2 = (const float*)d_in[10];
  const float* be2 = (const float*)d_in[11];
  const float* w3l = (const float*)d_in[12];
  const float* w3r = (const float*)d_in[13];
  const float* b3 = (const float*)d_in[14];

  char* ws = (char*)d_ws;
  size_t off = 0;
  auto alloc = [&](size_t bytes) {
    char* p = ws + off;
    off = (off + bytes + 255) & ~(size_t)255;
    return p;
  };
  unsigned short* xb = (unsigned short*)alloc((size_t)NN * DH * 2);
  unsigned short* meanb = (unsigned short*)alloc((size_t)NN * DH * 2);
  unsigned short* gbuf1 = (unsigned short*)alloc((size_t)NN * DH * 2);
  unsigned short* gbuf2 = (unsigned short*)alloc((size_t)NN * DH * 2);
  unsigned short* w1t = (unsigned short*)alloc(128 * 256 * 2);
  unsigned short* w2t = (unsigned short*)alloc(128 * 256 * 2);
  unsigned short* w3t = (unsigned short*)alloc(128 * 128 * 2);
  // zero region: bcnt | stats1 | stats2 (contiguous)
  int* bcnt = (int*)alloc(NBK * 4);
  float* stats1 = (float*)alloc(2 * DH * 4);
  float* stats2 = (float*)alloc(2 * DH * 4);
  size_t zlen = (char*)(stats2 + 2 * DH) - (char*)bcnt;
  int* deg = (int*)alloc(NN * 4);
  int* rowptr = (int*)alloc((NN + 1) * 4);
  int* adj = (int*)alloc((size_t)NE * 4);
  int* ebuf = (int*)alloc((size_t)NBK * CAPB * 4);
  float* invd = (float*)alloc(NN * 4);
  int* iscan = (int*)alloc(NN * 4);
  int* bsum = (int*)alloc(NB1 * 4);

  // ---- prep ----
  hipMemsetAsync(bcnt, 0, zlen, stream);
  k_prep<<<3445, 256, 0, stream>>>(x, w1l, w1r, w2l, w2r, w3l, w3r, xb, w1t, w2t, w3t);
  k_bucket<<<(NE + EPB - 1) / EPB, 256, 0, stream>>>(srcp, dstp, bcnt, ebuf);
  k_hist<<<NBK, 256, 0, stream>>>(bcnt, ebuf, deg, invd);
  k_scan1<<<NB1, 256, 0, stream>>>(deg, iscan, bsum);
  k_scan2<<<1, 256, 0, stream>>>(bsum);
  k_scan3<<<NB1, 256, 0, stream>>>(deg, iscan, bsum, rowptr);
  k_fill2<<<NBK, 256, 0, stream>>>(rowptr, bcnt, ebuf, adj);

  int agg_blocks = (NN * 64 + 255) / 256;
  int gemm_blocks = (NN + 127) / 128;

  // ---- layer 1 ----
  k_agg<false><<<agg_blocks, 256, 0, stream>>>(xb, rowptr, adj, invd, nullptr, nullptr, nullptr, meanb);
  k_gemm<true, true, false><<<gemm_blocks, 256, 0, stream>>>(
      meanb, xb, w1t, b1, nullptr, nullptr, nullptr, gbuf1, stats1);

  // ---- layer 2 (BN1+ReLU fused into agg and gemm A-load) ----
  k_agg<true><<<agg_blocks, 256, 0, stream>>>(gbuf1, rowptr, adj, invd, stats1, g1, be1, meanb);
  k_gemm<true, true, true><<<gemm_blocks, 256, 0, stream>>>(
      meanb, gbuf1, w2t, b2, stats1, g1, be1, gbuf2, stats2);

  // ---- layer 3: transform-first (BN2+ReLU fused into gemm A-load), then aggregate ----
  k_gemm<false, false, true><<<gemm_blocks, 256, 0, stream>>>(
      gbuf2, nullptr, w3t, nullptr, stats2, g2, be2, gbuf1, nullptr);
  k_agg3<<<agg_blocks, 256, 0, stream>>>(gbuf1, rowptr, adj, invd, b3, (float*)d_out);
}